// Round 1
// baseline (2288.925 us; speedup 1.0000x reference)
//
#include <hip/hip_runtime.h>

typedef __attribute__((ext_vector_type(8))) short short8;
typedef __attribute__((ext_vector_type(4))) float f32x4;
typedef unsigned short u16;
typedef unsigned int u32;

__device__ __forceinline__ u16 f2bf(float f) {
  u32 u = __float_as_uint(f);
  u = (u + 0x7fffu + ((u >> 16) & 1u)) >> 16;
  return (u16)u;
}
__device__ __forceinline__ void atomAddF(float* p, float v) { unsafeAtomicAdd(p, v); }
__device__ __forceinline__ u32 fflip(float f) {
  u32 u = __float_as_uint(f);
  return (u & 0x80000000u) ? ~u : (u | 0x80000000u);
}
__device__ __forceinline__ float funflip(u32 u) {
  return __uint_as_float((u & 0x80000000u) ? (u ^ 0x80000000u) : ~u);
}

// ---- setup: pack bf16 weights (MFMA B-frag layout) + find graph boundaries ----
__global__ void setup_k(const float* __restrict__ Wm1, const float* __restrict__ We1,
                        const float* __restrict__ Ws1, const float* __restrict__ Wm2,
                        const int* __restrict__ batch, u16* __restrict__ Wp1,
                        u16* __restrict__ Wp2, int* __restrict__ gstart,
                        int* __restrict__ gend, int N) {
  int tid = blockIdx.x * 256 + threadIdx.x;
  if (tid < 64 * 192) {  // Wcat1 = [Wm1(16); We1(4); Ws1(16)] rows, pad K to 64
    int k = tid / 192, n = tid % 192;
    float v = 0.f;
    if (k < 16) v = Wm1[k * 192 + n];
    else if (k < 20) v = We1[(k - 16) * 192 + n];
    else if (k < 36) v = Ws1[(k - 20) * 192 + n];
    Wp1[((k >> 3) * 192 + n) * 8 + (k & 7)] = f2bf(v);
  }
  if (tid < 224 * 208) {  // W_msg2, pad K 208->224
    int k = tid / 208, n = tid % 208;
    float v = (k < 208) ? Wm2[k * 208 + n] : 0.f;
    Wp2[((k >> 3) * 208 + n) * 8 + (k & 7)] = f2bf(v);
  }
  if (tid < N) {  // batch is sorted -> unique writers, no atomics
    int b = batch[tid];
    if (tid == 0 || batch[tid - 1] != b) gstart[b] = tid;
    if (tid == N - 1 || batch[tid + 1] != b) gend[b] = tid;
  }
}

// ---- edge pass 1: acc1[dst] += [x[src](16), ea(4), 1] ----
__global__ void edge1_k(const int* __restrict__ ei, const float* __restrict__ x,
                        const float* __restrict__ ea, float* __restrict__ acc1, int E) {
  int e = blockIdx.x * 256 + threadIdx.x;
  if (e >= E) return;
  int s = ei[e], d = ei[E + e];
  const float4* xs = (const float4*)(x + (size_t)s * 16);
  float4 a = xs[0], b = xs[1], c = xs[2], dd = xs[3];
  float4 w = *(const float4*)(ea + (size_t)e * 4);
  float* p = acc1 + (size_t)d * 24;
  atomAddF(p + 0, a.x);  atomAddF(p + 1, a.y);  atomAddF(p + 2, a.z);  atomAddF(p + 3, a.w);
  atomAddF(p + 4, b.x);  atomAddF(p + 5, b.y);  atomAddF(p + 6, b.z);  atomAddF(p + 7, b.w);
  atomAddF(p + 8, c.x);  atomAddF(p + 9, c.y);  atomAddF(p + 10, c.z); atomAddF(p + 11, c.w);
  atomAddF(p + 12, dd.x); atomAddF(p + 13, dd.y); atomAddF(p + 14, dd.z); atomAddF(p + 15, dd.w);
  atomAddF(p + 16, w.x); atomAddF(p + 17, w.y); atomAddF(p + 18, w.z); atomAddF(p + 19, w.w);
  atomAddF(p + 20, 1.0f);
}

// ---- edge pass 2: acc2[dst] += acc1[src][0..20] ----
__global__ void edge2_k(const int* __restrict__ ei, const float* __restrict__ acc1,
                        float* __restrict__ acc2, int E) {
  int e = blockIdx.x * 256 + threadIdx.x;
  if (e >= E) return;
  int s = ei[e], d = ei[E + e];
  const float4* ap = (const float4*)(acc1 + (size_t)s * 24);
  float4 v0 = ap[0], v1 = ap[1], v2 = ap[2], v3 = ap[3], v4 = ap[4];
  float dg = acc1[(size_t)s * 24 + 20];
  float* p = acc2 + (size_t)d * 24;
  atomAddF(p + 0, v0.x);  atomAddF(p + 1, v0.y);  atomAddF(p + 2, v0.z);  atomAddF(p + 3, v0.w);
  atomAddF(p + 4, v1.x);  atomAddF(p + 5, v1.y);  atomAddF(p + 6, v1.z);  atomAddF(p + 7, v1.w);
  atomAddF(p + 8, v2.x);  atomAddF(p + 9, v2.y);  atomAddF(p + 10, v2.z); atomAddF(p + 11, v2.w);
  atomAddF(p + 12, v3.x); atomAddF(p + 13, v3.y); atomAddF(p + 14, v3.z); atomAddF(p + 15, v3.w);
  atomAddF(p + 16, v4.x); atomAddF(p + 17, v4.y); atomAddF(p + 18, v4.z); atomAddF(p + 19, v4.w);
  atomAddF(p + 20, dg);
}

// ---- U1 build (bf16 [sx,sea,x] pad 64) + h1pre bias prefill ---- block=192, grid=N
__global__ void u1h1_k(const float* __restrict__ acc1, const float* __restrict__ x,
                       u16* __restrict__ U, float* __restrict__ h1pre,
                       const float* __restrict__ bm1, const float* __restrict__ be1,
                       const float* __restrict__ bs1) {
  int n = blockIdx.x, t = threadIdx.x;
  if (t < 64) {
    float v = 0.f;
    if (t < 20) v = acc1[(size_t)n * 24 + t];
    else if (t < 36) v = x[(size_t)n * 16 + (t - 20)];
    U[(size_t)n * 64 + t] = f2bf(v);
  }
  float deg = acc1[(size_t)n * 24 + 20];
  h1pre[(size_t)n * 192 + t] = deg * (bm1[t] + be1[t]) + bs1[t];
}

// ---- U2 build (bf16 [sx2,sea2,sx] pad 64) + V tail cols [192..224) ---- block=192, grid=N
__global__ void u2v_k(const float* __restrict__ acc1, const float* __restrict__ acc2,
                      u16* __restrict__ U, u16* __restrict__ V) {
  int n = blockIdx.x, t = threadIdx.x;
  if (t < 64) {
    float v = 0.f;
    if (t < 20) v = acc2[(size_t)n * 24 + t];
    else if (t < 36) v = acc1[(size_t)n * 24 + (t - 20)];
    U[(size_t)n * 64 + t] = f2bf(v);
  }
  if (t < 32) {
    float v = (t < 16) ? acc1[(size_t)n * 24 + t] : 0.f;
    V[(size_t)n * 224 + 192 + t] = f2bf(v);
  }
}

// ---- generic bf16 MFMA GEMM: C[M,Nc] += A[M,Kpad] @ Bpacked ---- block=64(1 wave), grid=(M/16, Nc/16)
__global__ void gemm_k(const u16* __restrict__ A, const u16* __restrict__ Bp,
                       float* __restrict__ C, int Kpad, int Nc) {
  int lane = threadIdx.x;
  int mt = blockIdx.x, nt = blockIdx.y;
  int rc = lane & 15, qd = lane >> 4;
  f32x4 acc = {0.f, 0.f, 0.f, 0.f};
  const u16* Ap = A + (size_t)(mt * 16 + rc) * Kpad + qd * 8;
  const u16* Bq = Bp + (size_t)(qd * Nc + nt * 16 + rc) * 8;
  int kbn = Kpad >> 5;
  for (int kb = 0; kb < kbn; ++kb) {
    short8 av = *(const short8*)(Ap + kb * 32);
    short8 bv = *(const short8*)(Bq + (size_t)kb * 4 * Nc * 8);
    acc = __builtin_amdgcn_mfma_f32_16x16x32_bf16(av, bv, acc, 0, 0, 0);
  }
  int m0 = mt * 16 + qd * 4;
  size_t base = (size_t)m0 * Nc + nt * 16 + rc;
#pragma unroll
  for (int r = 0; r < 4; ++r) C[base + (size_t)r * Nc] += acc[r];
}

// ---- fused q-GEMM: V[.,0..192) = bf16((U2@Wcat1 + sdeg*b12 + deg*bs1)*s1 + deg*t1) ----
__global__ void gemmq_k(const u16* __restrict__ A, const u16* __restrict__ Bp,
                        const float* __restrict__ acc1, const float* __restrict__ acc2,
                        const float* __restrict__ bm1, const float* __restrict__ be1,
                        const float* __restrict__ bs1, const float* __restrict__ st,
                        u16* __restrict__ V) {
  int lane = threadIdx.x;
  int mt = blockIdx.x, nt = blockIdx.y;
  int rc = lane & 15, qd = lane >> 4;
  f32x4 acc = {0.f, 0.f, 0.f, 0.f};
  const u16* Ap = A + (size_t)(mt * 16 + rc) * 64 + qd * 8;
  const u16* Bq = Bp + (size_t)(qd * 192 + nt * 16 + rc) * 8;
#pragma unroll
  for (int kb = 0; kb < 2; ++kb) {
    short8 av = *(const short8*)(Ap + kb * 32);
    short8 bv = *(const short8*)(Bq + (size_t)kb * 4 * 192 * 8);
    acc = __builtin_amdgcn_mfma_f32_16x16x32_bf16(av, bv, acc, 0, 0, 0);
  }
  int col = nt * 16 + rc;
  float sc = st[col], sh = st[192 + col];
  float bsum = bm1[col] + be1[col], bself = bs1[col];
  int m0 = mt * 16 + qd * 4;
#pragma unroll
  for (int r = 0; r < 4; ++r) {
    int m = m0 + r;
    float deg = acc1[(size_t)m * 24 + 20];
    float sdeg = acc2[(size_t)m * 24 + 20];
    float qv = acc[r] + sdeg * bsum + deg * bself;
    V[(size_t)m * 224 + col] = f2bf(qv * sc + deg * sh);
  }
}

// ---- h2pre prefill: sea1@We2 + deg*(bm2+be2) + x1[n] ---- block=208, grid=N
__global__ void h2pre_k(const float* __restrict__ acc1, const float* __restrict__ h1pre,
                        const float* __restrict__ x, const float* __restrict__ We2,
                        const float* __restrict__ bm2, const float* __restrict__ be2,
                        const float* __restrict__ st, float* __restrict__ h2pre) {
  int n = blockIdx.x, t = threadIdx.x;
  float deg = acc1[(size_t)n * 24 + 20];
  float e0 = acc1[(size_t)n * 24 + 16], e1 = acc1[(size_t)n * 24 + 17];
  float e2 = acc1[(size_t)n * 24 + 18], e3 = acc1[(size_t)n * 24 + 19];
  float x1n = (t < 192) ? (h1pre[(size_t)n * 192 + t] * st[t] + st[192 + t])
                        : x[(size_t)n * 16 + (t - 192)];
  h2pre[(size_t)n * 208 + t] = e0 * We2[t] + e1 * We2[208 + t] + e2 * We2[416 + t] +
                               e3 * We2[624 + t] + deg * (bm2[t] + be2[t]) + x1n;
}

// ---- BN column reduce: sums[c], sums[C+c] ---- block=256, grid=ceil(N/128)
__global__ void bnred_k(const float* __restrict__ h, int N, int C, float* __restrict__ sums) {
  int t = threadIdx.x;
  if (t >= C) return;
  int r0 = blockIdx.x * 128;
  int r1 = min(r0 + 128, N);
  float s = 0.f, ss = 0.f;
  for (int n = r0; n < r1; ++n) {
    float v = h[(size_t)n * C + t];
    s += v;
    ss += v * v;
  }
  atomAddF(&sums[t], s);
  atomAddF(&sums[C + t], ss);
}

__global__ void bnfin_k(const float* __restrict__ sums, const float* __restrict__ g,
                        const float* __restrict__ be, int C, float Ninv, float* __restrict__ st) {
  int t = threadIdx.x;
  if (t >= C) return;
  float m = sums[t] * Ninv;
  float v = sums[C + t] * Ninv - m * m;
  float s = g[t] * rsqrtf(v + 1e-5f);
  st[t] = s;
  st[C + t] = be[t] - m * s;
}

// ---- pooling: x2 on the fly, sum + max per graph ---- grid=(64,8), block=256
__global__ void pool_k(const float* __restrict__ h2pre, const float* __restrict__ h1pre,
                       const float* __restrict__ x, const float* __restrict__ st,
                       const int* __restrict__ gstart, const int* __restrict__ gend,
                       float* __restrict__ psum, u32* __restrict__ pmaxu) {
  int b = blockIdx.x, sub = blockIdx.y;
  int s0 = gstart[b], e0 = gend[b];
  if (s0 > e0) return;
  int cnt = e0 - s0 + 1;
  int per = (cnt + 7) >> 3;
  int n0 = s0 + sub * per;
  int n1 = min(n0 + per, e0 + 1);
  if (n0 >= n1) return;
  const float* st1 = st;
  const float* st2 = st + 384;
  for (int f = threadIdx.x; f < 416; f += 256) {
    const float* src;
    int stride;
    float sc, sh;
    if (f < 208) { src = h2pre + f; stride = 208; sc = st2[f]; sh = st2[208 + f]; }
    else if (f < 400) { int j = f - 208; src = h1pre + j; stride = 192; sc = st1[j]; sh = st1[192 + j]; }
    else { src = x + (f - 400); stride = 16; sc = 1.f; sh = 0.f; }
    float s = 0.f, mx = -3.4e38f;
    for (int n = n0; n < n1; ++n) {
      float v = src[(size_t)n * stride] * sc + sh;
      s += v;
      mx = fmaxf(mx, v);
    }
    atomAddF(&psum[b * 416 + f], s);
    atomicMax(&pmaxu[b * 416 + f], fflip(mx));
  }
}

// ---- MLP head + log_softmax ---- grid=64, block=256
__global__ void mlp_k(const float* __restrict__ psum, const u32* __restrict__ pmaxu,
                      const int* __restrict__ gstart, const int* __restrict__ gend,
                      const float* __restrict__ W1, const float* __restrict__ b1,
                      const float* __restrict__ al, const float* __restrict__ W2,
                      const float* __restrict__ b2, float* __restrict__ out) {
  __shared__ __align__(16) float pooled[1248];
  __shared__ float hid[624];
  __shared__ float logits[2];
  int b = blockIdx.x, t = threadIdx.x;
  int cnt = gend[b] - gstart[b] + 1;
  float inv = 1.f / (float)max(cnt, 1);
  for (int f = t; f < 416; f += 256) {
    float s = psum[b * 416 + f];
    float m = funflip(pmaxu[b * 416 + f]);
    pooled[f] = s;
    pooled[416 + f] = (cnt > 0) ? m : 0.f;
    pooled[832 + f] = s * inv;
  }
  __syncthreads();
  float alpha = al[0];
  for (int j = t; j < 624; j += 256) {
    float acc = b1[j];
    for (int k = 0; k < 1248; k += 4) {
      float4 p = *(const float4*)&pooled[k];
      acc += p.x * W1[(size_t)k * 624 + j] + p.y * W1[(size_t)(k + 1) * 624 + j] +
             p.z * W1[(size_t)(k + 2) * 624 + j] + p.w * W1[(size_t)(k + 3) * 624 + j];
    }
    hid[j] = acc >= 0.f ? acc : alpha * acc;
  }
  __syncthreads();
  if (t < 2) {
    float acc = b2[t];
    for (int k = 0; k < 624; ++k) acc += hid[k] * W2[k * 2 + t];
    logits[t] = acc;
  }
  __syncthreads();
  if (t < 2) {
    float l0 = logits[0], l1 = logits[1];
    float m = fmaxf(l0, l1);
    float lse = m + logf(expf(l0 - m) + expf(l1 - m));
    out[b * 2 + t] = logits[t] - lse;
  }
}

extern "C" void kernel_launch(void* const* d_in, const int* in_sizes, int n_in,
                              void* d_out, int out_size, void* d_ws, size_t ws_size,
                              hipStream_t stream) {
  const float* x = (const float*)d_in[0];
  const int* ei = (const int*)d_in[1];
  const float* ea = (const float*)d_in[2];
  const int* batch = (const int*)d_in[3];
  const float* Wm1 = (const float*)d_in[4];
  const float* bm1 = (const float*)d_in[5];
  const float* We1 = (const float*)d_in[6];
  const float* be1 = (const float*)d_in[7];
  const float* Ws1 = (const float*)d_in[8];
  const float* bs1 = (const float*)d_in[9];
  const float* g1 = (const float*)d_in[10];
  const float* bta1 = (const float*)d_in[11];
  const float* Wm2 = (const float*)d_in[12];
  const float* bm2 = (const float*)d_in[13];
  const float* We2 = (const float*)d_in[14];
  const float* be2 = (const float*)d_in[15];
  const float* g2 = (const float*)d_in[16];
  const float* bta2 = (const float*)d_in[17];
  const float* Wl1 = (const float*)d_in[18];
  const float* bl1 = (const float*)d_in[19];
  const float* alpha = (const float*)d_in[20];
  const float* Wl2 = (const float*)d_in[21];
  const float* bl2 = (const float*)d_in[22];
  float* out = (float*)d_out;

  const int N = in_sizes[3];      // 50000
  const int E = in_sizes[2] / 4;  // 800000
  const int MT = N / 16;          // 3125

  float* ws = (float*)d_ws;
  size_t o = 0;
  float* acc1 = ws + o;  o += (size_t)N * 24;
  float* acc2 = ws + o;  o += (size_t)N * 24;
  float* h1pre = ws + o; o += (size_t)N * 192;
  float* h2pre = ws + o; o += (size_t)N * 208;
  u16* U = (u16*)(ws + o);  o += (size_t)N * 32;   // N*64 u16
  u16* V = (u16*)(ws + o);  o += (size_t)N * 112;  // N*224 u16
  u16* Wp1 = (u16*)(ws + o); o += 6144;            // 64*192 u16
  u16* Wp2 = (u16*)(ws + o); o += 23296;           // 224*208 u16
  float* bns = ws + o;   o += 800;                 // bn1 sums(384) | bn2 sums(416)
  float* st = ws + o;    o += 800;                 // s1t1(384) | s2t2(416)
  float* psum = ws + o;  o += 64 * 416;
  u32* pmaxu = (u32*)(ws + o); o += 64 * 416;
  int* gstart = (int*)(ws + o); o += 64;
  int* gend = (int*)(ws + o);   o += 64;

  hipMemsetAsync(acc1, 0, (size_t)N * 48 * sizeof(float), stream);
  hipMemsetAsync(bns, 0, (size_t)(800 + 800 + 2 * 64 * 416) * sizeof(float), stream);

  int sb = (N + 255) / 256;  // 196 >= 224*208/256
  setup_k<<<sb, 256, 0, stream>>>(Wm1, We1, Ws1, Wm2, batch, Wp1, Wp2, gstart, gend, N);
  edge1_k<<<(E + 255) / 256, 256, 0, stream>>>(ei, x, ea, acc1, E);
  u1h1_k<<<N, 192, 0, stream>>>(acc1, x, U, h1pre, bm1, be1, bs1);
  gemm_k<<<dim3(MT, 12), 64, 0, stream>>>(U, Wp1, h1pre, 64, 192);
  bnred_k<<<(N + 127) / 128, 256, 0, stream>>>(h1pre, N, 192, bns);
  bnfin_k<<<1, 256, 0, stream>>>(bns, g1, bta1, 192, 1.f / (float)N, st);
  edge2_k<<<(E + 255) / 256, 256, 0, stream>>>(ei, acc1, acc2, E);
  u2v_k<<<N, 192, 0, stream>>>(acc1, acc2, U, V);
  gemmq_k<<<dim3(MT, 12), 64, 0, stream>>>(U, Wp1, acc1, acc2, bm1, be1, bs1, st, V);
  h2pre_k<<<N, 208, 0, stream>>>(acc1, h1pre, x, We2, bm2, be2, st, h2pre);
  gemm_k<<<dim3(MT, 13), 64, 0, stream>>>(V, Wp2, h2pre, 224, 208);
  bnred_k<<<(N + 127) / 128, 256, 0, stream>>>(h2pre, N, 208, bns + 384);
  bnfin_k<<<1, 256, 0, stream>>>(bns + 384, g2, bta2, 208, 1.f / (float)N, st + 384);
  pool_k<<<dim3(64, 8), 256, 0, stream>>>(h2pre, h1pre, x, st, gstart, gend, psum, pmaxu);
  mlp_k<<<64, 256, 0, stream>>>(psum, pmaxu, gstart, gend, Wl1, bl1, alpha, Wl2, bl2, out);
}

// Round 2
// 704.237 us; speedup vs baseline: 3.2502x; 3.2502x over previous
//
#include <hip/hip_runtime.h>

typedef __attribute__((ext_vector_type(8))) short short8;
typedef __attribute__((ext_vector_type(4))) float f32x4;
typedef unsigned short u16;
typedef unsigned int u32;

__device__ __forceinline__ u16 f2bf(float f) {
  u32 u = __float_as_uint(f);
  u = (u + 0x7fffu + ((u >> 16) & 1u)) >> 16;
  return (u16)u;
}
__device__ __forceinline__ void atomAddF(float* p, float v) { unsafeAtomicAdd(p, v); }
__device__ __forceinline__ u32 fflip(float f) {
  u32 u = __float_as_uint(f);
  return (u & 0x80000000u) ? ~u : (u | 0x80000000u);
}
__device__ __forceinline__ float funflip(u32 u) {
  return __uint_as_float((u & 0x80000000u) ? (u ^ 0x80000000u) : ~u);
}
__device__ __forceinline__ void add4(float4& a, const float4 b) {
  a.x += b.x; a.y += b.y; a.z += b.z; a.w += b.w;
}

// ---- setup: pack bf16 weights (MFMA B-frag layout) + find graph boundaries ----
__global__ void setup_k(const float* __restrict__ Wm1, const float* __restrict__ We1,
                        const float* __restrict__ Ws1, const float* __restrict__ Wm2,
                        const int* __restrict__ batch, u16* __restrict__ Wp1,
                        u16* __restrict__ Wp2, int* __restrict__ gstart,
                        int* __restrict__ gend, int N) {
  int tid = blockIdx.x * 256 + threadIdx.x;
  if (tid < 64 * 192) {  // Wcat1 = [Wm1(16); We1(4); Ws1(16)] rows, pad K to 64
    int k = tid / 192, n = tid % 192;
    float v = 0.f;
    if (k < 16) v = Wm1[k * 192 + n];
    else if (k < 20) v = We1[(k - 16) * 192 + n];
    else if (k < 36) v = Ws1[(k - 20) * 192 + n];
    Wp1[((k >> 3) * 192 + n) * 8 + (k & 7)] = f2bf(v);
  }
  if (tid < 224 * 208) {  // W_msg2, pad K 208->224
    int k = tid / 208, n = tid % 208;
    float v = (k < 208) ? Wm2[k * 208 + n] : 0.f;
    Wp2[((k >> 3) * 208 + n) * 8 + (k & 7)] = f2bf(v);
  }
  if (tid < N) {  // batch sorted -> unique writers
    int b = batch[tid];
    if (tid == 0 || batch[tid - 1] != b) gstart[b] = tid;
    if (tid == N - 1 || batch[tid + 1] != b) gend[b] = tid;
  }
}

// ---- CSR build: count -> scan -> scatter ----
__global__ void count_k(const int* __restrict__ ei, int* __restrict__ deg, int E) {
  int e = blockIdx.x * 256 + threadIdx.x;
  if (e >= E) return;
  atomicAdd(&deg[ei[E + e]], 1);
}

__global__ void scanA_k(const int* __restrict__ deg, int* __restrict__ bsum, int N) {
  __shared__ int sh[256];
  int t = threadIdx.x;
  int i = blockIdx.x * 256 + t;
  sh[t] = (i < N) ? deg[i] : 0;
  __syncthreads();
  for (int off = 128; off > 0; off >>= 1) {
    if (t < off) sh[t] += sh[t + off];
    __syncthreads();
  }
  if (t == 0) bsum[blockIdx.x] = sh[0];
}

__global__ void scanB_k(int* __restrict__ bsum, int nb) {  // nb <= 256, 1 block
  __shared__ int sh[256];
  int t = threadIdx.x;
  int v = (t < nb) ? bsum[t] : 0;
  sh[t] = v;
  __syncthreads();
  for (int off = 1; off < 256; off <<= 1) {
    int u = (t >= off) ? sh[t - off] : 0;
    __syncthreads();
    sh[t] += u;
    __syncthreads();
  }
  if (t < nb) bsum[t] = sh[t] - v;  // exclusive
}

__global__ void scanC_k(const int* __restrict__ deg, const int* __restrict__ bsum,
                        int* __restrict__ rowptr, int* __restrict__ cur, int N) {
  __shared__ int sh[256];
  int t = threadIdx.x;
  int i = blockIdx.x * 256 + t;
  int d = (i < N) ? deg[i] : 0;
  sh[t] = d;
  __syncthreads();
  for (int off = 1; off < 256; off <<= 1) {
    int u = (t >= off) ? sh[t - off] : 0;
    __syncthreads();
    sh[t] += u;
    __syncthreads();
  }
  int excl = sh[t] - d + bsum[blockIdx.x];
  if (i < N) {
    rowptr[i] = excl;
    cur[i] = excl;
    if (i == N - 1) rowptr[N] = excl + d;
  }
}

__global__ void scatter_k(const int* __restrict__ ei, int* __restrict__ cur,
                          int2* __restrict__ se, int E) {
  int e = blockIdx.x * 256 + threadIdx.x;
  if (e >= E) return;
  int s = ei[e], d = ei[E + e];
  int slot = atomicAdd(&cur[d], 1);
  se[slot] = make_int2(s, e);
}

// ---- gather pass 1: acc1[n] = [sum x[src](16), sum ea(4), deg] ---- thread/node
__global__ void gather1_k(const int2* __restrict__ se, const int* __restrict__ rowptr,
                          const float* __restrict__ x, const float* __restrict__ ea,
                          float* __restrict__ acc1, int N) {
  int n = blockIdx.x * 64 + threadIdx.x;
  if (n >= N) return;
  int j0 = rowptr[n], j1 = rowptr[n + 1];
  float4 a0 = {0, 0, 0, 0}, a1 = a0, a2 = a0, a3 = a0, a4 = a0;
  for (int j = j0; j < j1; ++j) {
    int2 p = se[j];
    const float4* xs = (const float4*)(x + (size_t)p.x * 16);
    float4 w = *(const float4*)(ea + (size_t)p.y * 4);
    float4 t0 = xs[0], t1 = xs[1], t2 = xs[2], t3 = xs[3];
    add4(a0, t0); add4(a1, t1); add4(a2, t2); add4(a3, t3); add4(a4, w);
  }
  float4* out = (float4*)(acc1 + (size_t)n * 24);
  out[0] = a0; out[1] = a1; out[2] = a2; out[3] = a3; out[4] = a4;
  out[5] = make_float4((float)(j1 - j0), 0.f, 0.f, 0.f);
}

// ---- gather pass 2: acc2[n] = sum over in-edges of acc1[src][0..20] ---- thread/node
__global__ void gather2_k(const int2* __restrict__ se, const int* __restrict__ rowptr,
                          const float* __restrict__ acc1, float* __restrict__ acc2, int N) {
  int n = blockIdx.x * 64 + threadIdx.x;
  if (n >= N) return;
  int j0 = rowptr[n], j1 = rowptr[n + 1];
  float4 a0 = {0, 0, 0, 0}, a1 = a0, a2 = a0, a3 = a0, a4 = a0;
  float dg = 0.f;
  for (int j = j0; j < j1; ++j) {
    int s = se[j].x;
    const float4* ap = (const float4*)(acc1 + (size_t)s * 24);
    float4 t0 = ap[0], t1 = ap[1], t2 = ap[2], t3 = ap[3], t4 = ap[4], t5 = ap[5];
    add4(a0, t0); add4(a1, t1); add4(a2, t2); add4(a3, t3); add4(a4, t4);
    dg += t5.x;
  }
  float4* out = (float4*)(acc2 + (size_t)n * 24);
  out[0] = a0; out[1] = a1; out[2] = a2; out[3] = a3; out[4] = a4;
  out[5] = make_float4(dg, 0.f, 0.f, 0.f);
}

// ---- U1 build (bf16 [sx,sea,x] pad 64) + h1pre bias prefill ---- block=192, grid=N
__global__ void u1h1_k(const float* __restrict__ acc1, const float* __restrict__ x,
                       u16* __restrict__ U, float* __restrict__ h1pre,
                       const float* __restrict__ bm1, const float* __restrict__ be1,
                       const float* __restrict__ bs1) {
  int n = blockIdx.x, t = threadIdx.x;
  if (t < 64) {
    float v = 0.f;
    if (t < 20) v = acc1[(size_t)n * 24 + t];
    else if (t < 36) v = x[(size_t)n * 16 + (t - 20)];
    U[(size_t)n * 64 + t] = f2bf(v);
  }
  float deg = acc1[(size_t)n * 24 + 20];
  h1pre[(size_t)n * 192 + t] = deg * (bm1[t] + be1[t]) + bs1[t];
}

// ---- U2 build (bf16 [sx2,sea2,sx] pad 64) + V tail cols [192..224) ---- block=192, grid=N
__global__ void u2v_k(const float* __restrict__ acc1, const float* __restrict__ acc2,
                      u16* __restrict__ U, u16* __restrict__ V) {
  int n = blockIdx.x, t = threadIdx.x;
  if (t < 64) {
    float v = 0.f;
    if (t < 20) v = acc2[(size_t)n * 24 + t];
    else if (t < 36) v = acc1[(size_t)n * 24 + (t - 20)];
    U[(size_t)n * 64 + t] = f2bf(v);
  }
  if (t < 32) {
    float v = (t < 16) ? acc1[(size_t)n * 24 + t] : 0.f;
    V[(size_t)n * 224 + 192 + t] = f2bf(v);
  }
}

// ---- generic bf16 MFMA GEMM: C[M,Nc] += A[M,Kpad] @ Bpacked ---- block=64, grid=(M/16, Nc/16)
__global__ void gemm_k(const u16* __restrict__ A, const u16* __restrict__ Bp,
                       float* __restrict__ C, int Kpad, int Nc) {
  int lane = threadIdx.x;
  int mt = blockIdx.x, nt = blockIdx.y;
  int rc = lane & 15, qd = lane >> 4;
  f32x4 acc = {0.f, 0.f, 0.f, 0.f};
  const u16* Ap = A + (size_t)(mt * 16 + rc) * Kpad + qd * 8;
  const u16* Bq = Bp + (size_t)(qd * Nc + nt * 16 + rc) * 8;
  int kbn = Kpad >> 5;
  for (int kb = 0; kb < kbn; ++kb) {
    short8 av = *(const short8*)(Ap + kb * 32);
    short8 bv = *(const short8*)(Bq + (size_t)kb * 4 * Nc * 8);
    acc = __builtin_amdgcn_mfma_f32_16x16x32_bf16(av, bv, acc, 0, 0, 0);
  }
  int m0 = mt * 16 + qd * 4;
  size_t base = (size_t)m0 * Nc + nt * 16 + rc;
#pragma unroll
  for (int r = 0; r < 4; ++r) C[base + (size_t)r * Nc] += acc[r];
}

// ---- fused q-GEMM: V[.,0..192) = bf16((U2@Wcat1 + sdeg*b12 + deg*bs1)*s1 + deg*t1) ----
__global__ void gemmq_k(const u16* __restrict__ A, const u16* __restrict__ Bp,
                        const float* __restrict__ acc1, const float* __restrict__ acc2,
                        const float* __restrict__ bm1, const float* __restrict__ be1,
                        const float* __restrict__ bs1, const float* __restrict__ st,
                        u16* __restrict__ V) {
  int lane = threadIdx.x;
  int mt = blockIdx.x, nt = blockIdx.y;
  int rc = lane & 15, qd = lane >> 4;
  f32x4 acc = {0.f, 0.f, 0.f, 0.f};
  const u16* Ap = A + (size_t)(mt * 16 + rc) * 64 + qd * 8;
  const u16* Bq = Bp + (size_t)(qd * 192 + nt * 16 + rc) * 8;
#pragma unroll
  for (int kb = 0; kb < 2; ++kb) {
    short8 av = *(const short8*)(Ap + kb * 32);
    short8 bv = *(const short8*)(Bq + (size_t)kb * 4 * 192 * 8);
    acc = __builtin_amdgcn_mfma_f32_16x16x32_bf16(av, bv, acc, 0, 0, 0);
  }
  int col = nt * 16 + rc;
  float sc = st[col], sh = st[192 + col];
  float bsum = bm1[col] + be1[col], bself = bs1[col];
  int m0 = mt * 16 + qd * 4;
#pragma unroll
  for (int r = 0; r < 4; ++r) {
    int m = m0 + r;
    float deg = acc1[(size_t)m * 24 + 20];
    float sdeg = acc2[(size_t)m * 24 + 20];
    float qv = acc[r] + sdeg * bsum + deg * bself;
    V[(size_t)m * 224 + col] = f2bf(qv * sc + deg * sh);
  }
}

// ---- h2pre prefill: sea1@We2 + deg*(bm2+be2) + x1[n] ---- block=208, grid=N
__global__ void h2pre_k(const float* __restrict__ acc1, const float* __restrict__ h1pre,
                        const float* __restrict__ x, const float* __restrict__ We2,
                        const float* __restrict__ bm2, const float* __restrict__ be2,
                        const float* __restrict__ st, float* __restrict__ h2pre) {
  int n = blockIdx.x, t = threadIdx.x;
  float deg = acc1[(size_t)n * 24 + 20];
  float e0 = acc1[(size_t)n * 24 + 16], e1 = acc1[(size_t)n * 24 + 17];
  float e2 = acc1[(size_t)n * 24 + 18], e3 = acc1[(size_t)n * 24 + 19];
  float x1n = (t < 192) ? (h1pre[(size_t)n * 192 + t] * st[t] + st[192 + t])
                        : x[(size_t)n * 16 + (t - 192)];
  h2pre[(size_t)n * 208 + t] = e0 * We2[t] + e1 * We2[208 + t] + e2 * We2[416 + t] +
                               e3 * We2[624 + t] + deg * (bm2[t] + be2[t]) + x1n;
}

// ---- BN column reduce ---- block=256, grid=ceil(N/128)
__global__ void bnred_k(const float* __restrict__ h, int N, int C, float* __restrict__ sums) {
  int t = threadIdx.x;
  if (t >= C) return;
  int r0 = blockIdx.x * 128;
  int r1 = min(r0 + 128, N);
  float s = 0.f, ss = 0.f;
  for (int n = r0; n < r1; ++n) {
    float v = h[(size_t)n * C + t];
    s += v;
    ss += v * v;
  }
  atomAddF(&sums[t], s);
  atomAddF(&sums[C + t], ss);
}

__global__ void bnfin_k(const float* __restrict__ sums, const float* __restrict__ g,
                        const float* __restrict__ be, int C, float Ninv, float* __restrict__ st) {
  int t = threadIdx.x;
  if (t >= C) return;
  float m = sums[t] * Ninv;
  float v = sums[C + t] * Ninv - m * m;
  float s = g[t] * rsqrtf(v + 1e-5f);
  st[t] = s;
  st[C + t] = be[t] - m * s;
}

// ---- pooling: x2 on the fly, sum + max per graph ---- grid=(64,8), block=256
__global__ void pool_k(const float* __restrict__ h2pre, const float* __restrict__ h1pre,
                       const float* __restrict__ x, const float* __restrict__ st,
                       const int* __restrict__ gstart, const int* __restrict__ gend,
                       float* __restrict__ psum, u32* __restrict__ pmaxu) {
  int b = blockIdx.x, sub = blockIdx.y;
  int s0 = gstart[b], e0 = gend[b];
  if (s0 > e0) return;
  int cnt = e0 - s0 + 1;
  int per = (cnt + 7) >> 3;
  int n0 = s0 + sub * per;
  int n1 = min(n0 + per, e0 + 1);
  if (n0 >= n1) return;
  const float* st1 = st;
  const float* st2 = st + 384;
  for (int f = threadIdx.x; f < 416; f += 256) {
    const float* src;
    int stride;
    float sc, sh;
    if (f < 208) { src = h2pre + f; stride = 208; sc = st2[f]; sh = st2[208 + f]; }
    else if (f < 400) { int j = f - 208; src = h1pre + j; stride = 192; sc = st1[j]; sh = st1[192 + j]; }
    else { src = x + (f - 400); stride = 16; sc = 1.f; sh = 0.f; }
    float s = 0.f, mx = -3.4e38f;
    for (int n = n0; n < n1; ++n) {
      float v = src[(size_t)n * stride] * sc + sh;
      s += v;
      mx = fmaxf(mx, v);
    }
    atomAddF(&psum[b * 416 + f], s);
    atomicMax(&pmaxu[b * 416 + f], fflip(mx));
  }
}

// ---- MLP head + log_softmax ---- grid=64, block=256
__global__ void mlp_k(const float* __restrict__ psum, const u32* __restrict__ pmaxu,
                      const int* __restrict__ gstart, const int* __restrict__ gend,
                      const float* __restrict__ W1, const float* __restrict__ b1,
                      const float* __restrict__ al, const float* __restrict__ W2,
                      const float* __restrict__ b2, float* __restrict__ out) {
  __shared__ __align__(16) float pooled[1248];
  __shared__ float hid[624];
  __shared__ float logits[2];
  int b = blockIdx.x, t = threadIdx.x;
  int cnt = gend[b] - gstart[b] + 1;
  float inv = 1.f / (float)max(cnt, 1);
  for (int f = t; f < 416; f += 256) {
    float s = psum[b * 416 + f];
    float m = funflip(pmaxu[b * 416 + f]);
    pooled[f] = s;
    pooled[416 + f] = (cnt > 0) ? m : 0.f;
    pooled[832 + f] = s * inv;
  }
  __syncthreads();
  float alpha = al[0];
  for (int j = t; j < 624; j += 256) {
    float acc = b1[j];
    for (int k = 0; k < 1248; k += 4) {
      float4 p = *(const float4*)&pooled[k];
      acc += p.x * W1[(size_t)k * 624 + j] + p.y * W1[(size_t)(k + 1) * 624 + j] +
             p.z * W1[(size_t)(k + 2) * 624 + j] + p.w * W1[(size_t)(k + 3) * 624 + j];
    }
    hid[j] = acc >= 0.f ? acc : alpha * acc;
  }
  __syncthreads();
  if (t < 2) {
    float acc = b2[t];
    for (int k = 0; k < 624; ++k) acc += hid[k] * W2[k * 2 + t];
    logits[t] = acc;
  }
  __syncthreads();
  if (t < 2) {
    float l0 = logits[0], l1 = logits[1];
    float m = fmaxf(l0, l1);
    float lse = m + logf(expf(l0 - m) + expf(l1 - m));
    out[b * 2 + t] = logits[t] - lse;
  }
}

extern "C" void kernel_launch(void* const* d_in, const int* in_sizes, int n_in,
                              void* d_out, int out_size, void* d_ws, size_t ws_size,
                              hipStream_t stream) {
  const float* x = (const float*)d_in[0];
  const int* ei = (const int*)d_in[1];
  const float* ea = (const float*)d_in[2];
  const int* batch = (const int*)d_in[3];
  const float* Wm1 = (const float*)d_in[4];
  const float* bm1 = (const float*)d_in[5];
  const float* We1 = (const float*)d_in[6];
  const float* be1 = (const float*)d_in[7];
  const float* Ws1 = (const float*)d_in[8];
  const float* bs1 = (const float*)d_in[9];
  const float* g1 = (const float*)d_in[10];
  const float* bta1 = (const float*)d_in[11];
  const float* Wm2 = (const float*)d_in[12];
  const float* bm2 = (const float*)d_in[13];
  const float* We2 = (const float*)d_in[14];
  const float* be2 = (const float*)d_in[15];
  const float* g2 = (const float*)d_in[16];
  const float* bta2 = (const float*)d_in[17];
  const float* Wl1 = (const float*)d_in[18];
  const float* bl1 = (const float*)d_in[19];
  const float* alpha = (const float*)d_in[20];
  const float* Wl2 = (const float*)d_in[21];
  const float* bl2 = (const float*)d_in[22];
  float* out = (float*)d_out;

  const int N = in_sizes[3];      // 50000
  const int E = in_sizes[2] / 4;  // 800000
  const int MT = N / 16;          // 3125
  const int nb = (N + 255) / 256; // scan blocks (<=256 required)

  float* ws = (float*)d_ws;
  size_t o = 0;
  float* acc1 = ws + o;  o += (size_t)N * 24;
  float* acc2 = ws + o;  o += (size_t)N * 24;
  float* h1pre = ws + o; o += (size_t)N * 192;
  float* h2pre = ws + o; o += (size_t)N * 208;   // also aliased as CSR edge list (se)
  u16* U = (u16*)(ws + o);  o += (size_t)N * 32;   // N*64 u16
  u16* V = (u16*)(ws + o);  o += (size_t)N * 112;  // N*224 u16
  u16* Wp1 = (u16*)(ws + o); o += 6144;            // 64*192 u16
  u16* Wp2 = (u16*)(ws + o); o += 23296;           // 224*208 u16
  float* bns = ws + o;   o += 800;                 // bn1 sums(384) | bn2 sums(416)
  float* st = ws + o;    o += 800;                 // s1t1(384) | s2t2(416)
  float* psum = ws + o;  o += 64 * 416;
  u32* pmaxu = (u32*)(ws + o); o += 64 * 416;
  int* gstart = (int*)(ws + o); o += 64;
  int* gend = (int*)(ws + o);   o += 64;
  int* deg = (int*)(ws + o);    o += N;
  int* rowptr = (int*)(ws + o); o += N + 1;
  int* cur = (int*)(ws + o);    o += N + 1;
  int* bsum = (int*)(ws + o);   o += 256;
  int2* se = (int2*)h2pre;  // E int2 = 6.4 MB <= N*208*4B; h2pre written later

  hipMemsetAsync(deg, 0, (size_t)N * sizeof(int), stream);
  hipMemsetAsync(bns, 0, (size_t)(800 + 800 + 2 * 64 * 416) * sizeof(float), stream);

  int sb = (N + 255) / 256;  // 196 >= 224*208/256
  setup_k<<<sb, 256, 0, stream>>>(Wm1, We1, Ws1, Wm2, batch, Wp1, Wp2, gstart, gend, N);
  // CSR build
  count_k<<<(E + 255) / 256, 256, 0, stream>>>(ei, deg, E);
  scanA_k<<<nb, 256, 0, stream>>>(deg, bsum, N);
  scanB_k<<<1, 256, 0, stream>>>(bsum, nb);
  scanC_k<<<nb, 256, 0, stream>>>(deg, bsum, rowptr, cur, N);
  scatter_k<<<(E + 255) / 256, 256, 0, stream>>>(ei, cur, se, E);
  // layer 1
  gather1_k<<<(N + 63) / 64, 64, 0, stream>>>(se, rowptr, x, ea, acc1, N);
  u1h1_k<<<N, 192, 0, stream>>>(acc1, x, U, h1pre, bm1, be1, bs1);
  gemm_k<<<dim3(MT, 12), 64, 0, stream>>>(U, Wp1, h1pre, 64, 192);
  bnred_k<<<(N + 127) / 128, 256, 0, stream>>>(h1pre, N, 192, bns);
  bnfin_k<<<1, 256, 0, stream>>>(bns, g1, bta1, 192, 1.f / (float)N, st);
  // layer 2
  gather2_k<<<(N + 63) / 64, 64, 0, stream>>>(se, rowptr, acc1, acc2, N);
  u2v_k<<<N, 192, 0, stream>>>(acc1, acc2, U, V);
  gemmq_k<<<dim3(MT, 12), 64, 0, stream>>>(U, Wp1, acc1, acc2, bm1, be1, bs1, st, V);
  h2pre_k<<<N, 208, 0, stream>>>(acc1, h1pre, x, We2, bm2, be2, st, h2pre);
  gemm_k<<<dim3(MT, 13), 64, 0, stream>>>(V, Wp2, h2pre, 224, 208);
  bnred_k<<<(N + 127) / 128, 256, 0, stream>>>(h2pre, N, 208, bns + 384);
  bnfin_k<<<1, 256, 0, stream>>>(bns + 384, g2, bta2, 208, 1.f / (float)N, st + 384);
  // head
  pool_k<<<dim3(64, 8), 256, 0, stream>>>(h2pre, h1pre, x, st, gstart, gend, psum, pmaxu);
  mlp_k<<<64, 256, 0, stream>>>(psum, pmaxu, gstart, gend, Wl1, bl1, alpha, Wl2, bl2, out);
}

// Round 3
// 615.907 us; speedup vs baseline: 3.7163x; 1.1434x over previous
//
#include <hip/hip_runtime.h>

typedef __attribute__((ext_vector_type(8))) short short8;
typedef __attribute__((ext_vector_type(4))) float f32x4;
typedef unsigned short u16;
typedef unsigned int u32;

__device__ __forceinline__ u16 f2bf(float f) {
  u32 u = __float_as_uint(f);
  u = (u + 0x7fffu + ((u >> 16) & 1u)) >> 16;
  return (u16)u;
}
__device__ __forceinline__ void atomAddF(float* p, float v) { unsafeAtomicAdd(p, v); }
__device__ __forceinline__ u32 fflip(float f) {
  u32 u = __float_as_uint(f);
  return (u & 0x80000000u) ? ~u : (u | 0x80000000u);
}
__device__ __forceinline__ float funflip(u32 u) {
  return __uint_as_float((u & 0x80000000u) ? (u ^ 0x80000000u) : ~u);
}
__device__ __forceinline__ void add4(float4& a, const float4 b) {
  a.x += b.x; a.y += b.y; a.z += b.z; a.w += b.w;
}

// ---- setup: pack bf16 weights (MFMA B-frag layout) + find graph boundaries ----
__global__ void setup_k(const float* __restrict__ Wm1, const float* __restrict__ We1,
                        const float* __restrict__ Ws1, const float* __restrict__ Wm2,
                        const int* __restrict__ batch, u16* __restrict__ Wp1,
                        u16* __restrict__ Wp2, int* __restrict__ gstart,
                        int* __restrict__ gend, int N) {
  int tid = blockIdx.x * 256 + threadIdx.x;
  if (tid < 64 * 192) {  // Wcat1 = [Wm1(16); We1(4); Ws1(16)] rows, pad K to 64
    int k = tid / 192, n = tid % 192;
    float v = 0.f;
    if (k < 16) v = Wm1[k * 192 + n];
    else if (k < 20) v = We1[(k - 16) * 192 + n];
    else if (k < 36) v = Ws1[(k - 20) * 192 + n];
    Wp1[((k >> 3) * 192 + n) * 8 + (k & 7)] = f2bf(v);
  }
  if (tid < 224 * 208) {  // W_msg2, pad K 208->224
    int k = tid / 208, n = tid % 208;
    float v = (k < 208) ? Wm2[k * 208 + n] : 0.f;
    Wp2[((k >> 3) * 208 + n) * 8 + (k & 7)] = f2bf(v);
  }
  if (tid < N) {  // batch sorted -> unique writers
    int b = batch[tid];
    if (tid == 0 || batch[tid - 1] != b) gstart[b] = tid;
    if (tid == N - 1 || batch[tid + 1] != b) gend[b] = tid;
  }
}

// ---- pack W_l1 (1248x624) to bf16 B-frag layout ----
__global__ void pack1_k(const float* __restrict__ W1, u16* __restrict__ Wp3) {
  int tid = blockIdx.x * 256 + threadIdx.x;
  if (tid >= 1248 * 624) return;
  int k = tid / 624, n = tid % 624;
  Wp3[((size_t)(k >> 3) * 624 + n) * 8 + (k & 7)] = f2bf(W1[(size_t)k * 624 + n]);
}

// ---- CSR build: count -> scan -> scatter ----
__global__ void count_k(const int* __restrict__ ei, int* __restrict__ deg, int E) {
  int e = blockIdx.x * 256 + threadIdx.x;
  if (e >= E) return;
  atomicAdd(&deg[ei[E + e]], 1);
}

__global__ void scanA_k(const int* __restrict__ deg, int* __restrict__ bsum, int N) {
  __shared__ int sh[256];
  int t = threadIdx.x;
  int i = blockIdx.x * 256 + t;
  sh[t] = (i < N) ? deg[i] : 0;
  __syncthreads();
  for (int off = 128; off > 0; off >>= 1) {
    if (t < off) sh[t] += sh[t + off];
    __syncthreads();
  }
  if (t == 0) bsum[blockIdx.x] = sh[0];
}

__global__ void scanB_k(int* __restrict__ bsum, int nb) {  // nb <= 256, 1 block
  __shared__ int sh[256];
  int t = threadIdx.x;
  int v = (t < nb) ? bsum[t] : 0;
  sh[t] = v;
  __syncthreads();
  for (int off = 1; off < 256; off <<= 1) {
    int u = (t >= off) ? sh[t - off] : 0;
    __syncthreads();
    sh[t] += u;
    __syncthreads();
  }
  if (t < nb) bsum[t] = sh[t] - v;  // exclusive
}

__global__ void scanC_k(const int* __restrict__ deg, const int* __restrict__ bsum,
                        int* __restrict__ rowptr, int* __restrict__ cur, int N) {
  __shared__ int sh[256];
  int t = threadIdx.x;
  int i = blockIdx.x * 256 + t;
  int d = (i < N) ? deg[i] : 0;
  sh[t] = d;
  __syncthreads();
  for (int off = 1; off < 256; off <<= 1) {
    int u = (t >= off) ? sh[t - off] : 0;
    __syncthreads();
    sh[t] += u;
    __syncthreads();
  }
  int excl = sh[t] - d + bsum[blockIdx.x];
  if (i < N) {
    rowptr[i] = excl;
    cur[i] = excl;
    if (i == N - 1) rowptr[N] = excl + d;
  }
}

__global__ void scatter_k(const int* __restrict__ ei, int* __restrict__ cur,
                          int2* __restrict__ se, int E) {
  int e = blockIdx.x * 256 + threadIdx.x;
  if (e >= E) return;
  int s = ei[e], d = ei[E + e];
  int slot = atomicAdd(&cur[d], 1);
  se[slot] = make_int2(s, e);
}

// ---- gather pass 1: 4 lanes per node, quad shuffle-reduce ---- block=256
__global__ void gather1_k(const int2* __restrict__ se, const int* __restrict__ rowptr,
                          const float* __restrict__ x, const float* __restrict__ ea,
                          float* __restrict__ acc1, int N) {
  int tid = blockIdx.x * 256 + threadIdx.x;
  int n = tid >> 2, q = tid & 3;
  if (n >= N) return;
  int j0 = rowptr[n], j1 = rowptr[n + 1];
  float4 a0 = {0, 0, 0, 0}, a1 = a0, a2 = a0, a3 = a0, a4 = a0;
  for (int j = j0 + q; j < j1; j += 4) {
    int2 p = se[j];
    const float4* xs = (const float4*)(x + (size_t)p.x * 16);
    float4 w = *(const float4*)(ea + (size_t)p.y * 4);
    add4(a0, xs[0]); add4(a1, xs[1]); add4(a2, xs[2]); add4(a3, xs[3]); add4(a4, w);
  }
  float v[24] = {a0.x, a0.y, a0.z, a0.w, a1.x, a1.y, a1.z, a1.w,
                 a2.x, a2.y, a2.z, a2.w, a3.x, a3.y, a3.z, a3.w,
                 a4.x, a4.y, a4.z, a4.w, (float)(j1 - j0), 0.f, 0.f, 0.f};
#pragma unroll
  for (int i = 0; i < 20; ++i) {
    v[i] += __shfl_xor(v[i], 1);
    v[i] += __shfl_xor(v[i], 2);
  }
  float4* out = (float4*)(acc1 + (size_t)n * 24);
  out[q] = make_float4(v[q * 4], v[q * 4 + 1], v[q * 4 + 2], v[q * 4 + 3]);
  if (q < 2) out[4 + q] = make_float4(v[16 + q * 4], v[17 + q * 4], v[18 + q * 4], v[19 + q * 4]);
}

// ---- gather pass 2: acc2[n] = sum over in-edges of acc1[src][0..21) ---- block=256
__global__ void gather2_k(const int2* __restrict__ se, const int* __restrict__ rowptr,
                          const float* __restrict__ acc1, float* __restrict__ acc2, int N) {
  int tid = blockIdx.x * 256 + threadIdx.x;
  int n = tid >> 2, q = tid & 3;
  if (n >= N) return;
  int j0 = rowptr[n], j1 = rowptr[n + 1];
  float4 a0 = {0, 0, 0, 0}, a1 = a0, a2 = a0, a3 = a0, a4 = a0;
  float dg = 0.f;
  for (int j = j0 + q; j < j1; j += 4) {
    int s = se[j].x;
    const float4* ap = (const float4*)(acc1 + (size_t)s * 24);
    float4 t5 = ap[5];
    add4(a0, ap[0]); add4(a1, ap[1]); add4(a2, ap[2]); add4(a3, ap[3]); add4(a4, ap[4]);
    dg += t5.x;
  }
  float v[24] = {a0.x, a0.y, a0.z, a0.w, a1.x, a1.y, a1.z, a1.w,
                 a2.x, a2.y, a2.z, a2.w, a3.x, a3.y, a3.z, a3.w,
                 a4.x, a4.y, a4.z, a4.w, dg, 0.f, 0.f, 0.f};
#pragma unroll
  for (int i = 0; i < 21; ++i) {
    v[i] += __shfl_xor(v[i], 1);
    v[i] += __shfl_xor(v[i], 2);
  }
  float4* out = (float4*)(acc2 + (size_t)n * 24);
  out[q] = make_float4(v[q * 4], v[q * 4 + 1], v[q * 4 + 2], v[q * 4 + 3]);
  if (q < 2) out[4 + q] = make_float4(v[16 + q * 4], v[17 + q * 4], v[18 + q * 4], v[19 + q * 4]);
}

// ---- U1 build (bf16 [sx,sea,x] pad 64) + h1pre bias prefill ---- block=192, grid=N
__global__ void u1h1_k(const float* __restrict__ acc1, const float* __restrict__ x,
                       u16* __restrict__ U, float* __restrict__ h1pre,
                       const float* __restrict__ bm1, const float* __restrict__ be1,
                       const float* __restrict__ bs1) {
  int n = blockIdx.x, t = threadIdx.x;
  if (t < 64) {
    float v = 0.f;
    if (t < 20) v = acc1[(size_t)n * 24 + t];
    else if (t < 36) v = x[(size_t)n * 16 + (t - 20)];
    U[(size_t)n * 64 + t] = f2bf(v);
  }
  float deg = acc1[(size_t)n * 24 + 20];
  h1pre[(size_t)n * 192 + t] = deg * (bm1[t] + be1[t]) + bs1[t];
}

// ---- U2 build (bf16 [sx2,sea2,sx] pad 64) + V tail cols [192..224) ---- block=192, grid=N
__global__ void u2v_k(const float* __restrict__ acc1, const float* __restrict__ acc2,
                      u16* __restrict__ U, u16* __restrict__ V) {
  int n = blockIdx.x, t = threadIdx.x;
  if (t < 64) {
    float v = 0.f;
    if (t < 20) v = acc2[(size_t)n * 24 + t];
    else if (t < 36) v = acc1[(size_t)n * 24 + (t - 20)];
    U[(size_t)n * 64 + t] = f2bf(v);
  }
  if (t < 32) {
    float v = (t < 16) ? acc1[(size_t)n * 24 + t] : 0.f;
    V[(size_t)n * 224 + 192 + t] = f2bf(v);
  }
}

// ---- generic bf16 MFMA GEMM: C[M,Nc] += A[M,Kpad] @ Bpacked ---- block=64, grid=(M/16, Nc/16)
__global__ void gemm_k(const u16* __restrict__ A, const u16* __restrict__ Bp,
                       float* __restrict__ C, int Kpad, int Nc) {
  int lane = threadIdx.x;
  int mt = blockIdx.x, nt = blockIdx.y;
  int rc = lane & 15, qd = lane >> 4;
  f32x4 acc = {0.f, 0.f, 0.f, 0.f};
  const u16* Ap = A + (size_t)(mt * 16 + rc) * Kpad + qd * 8;
  const u16* Bq = Bp + (size_t)(qd * Nc + nt * 16 + rc) * 8;
  int kbn = Kpad >> 5;
  for (int kb = 0; kb < kbn; ++kb) {
    short8 av = *(const short8*)(Ap + kb * 32);
    short8 bv = *(const short8*)(Bq + (size_t)kb * 4 * Nc * 8);
    acc = __builtin_amdgcn_mfma_f32_16x16x32_bf16(av, bv, acc, 0, 0, 0);
  }
  int m0 = mt * 16 + qd * 4;
  size_t base = (size_t)m0 * Nc + nt * 16 + rc;
#pragma unroll
  for (int r = 0; r < 4; ++r) C[base + (size_t)r * Nc] += acc[r];
}

// ---- fused q-GEMM: V[.,0..192) = bf16((U2@Wcat1 + sdeg*b12 + deg*bs1)*s1 + deg*t1) ----
__global__ void gemmq_k(const u16* __restrict__ A, const u16* __restrict__ Bp,
                        const float* __restrict__ acc1, const float* __restrict__ acc2,
                        const float* __restrict__ bm1, const float* __restrict__ be1,
                        const float* __restrict__ bs1, const float* __restrict__ st,
                        u16* __restrict__ V) {
  int lane = threadIdx.x;
  int mt = blockIdx.x, nt = blockIdx.y;
  int rc = lane & 15, qd = lane >> 4;
  f32x4 acc = {0.f, 0.f, 0.f, 0.f};
  const u16* Ap = A + (size_t)(mt * 16 + rc) * 64 + qd * 8;
  const u16* Bq = Bp + (size_t)(qd * 192 + nt * 16 + rc) * 8;
#pragma unroll
  for (int kb = 0; kb < 2; ++kb) {
    short8 av = *(const short8*)(Ap + kb * 32);
    short8 bv = *(const short8*)(Bq + (size_t)kb * 4 * 192 * 8);
    acc = __builtin_amdgcn_mfma_f32_16x16x32_bf16(av, bv, acc, 0, 0, 0);
  }
  int col = nt * 16 + rc;
  float sc = st[col], sh = st[192 + col];
  float bsum = bm1[col] + be1[col], bself = bs1[col];
  int m0 = mt * 16 + qd * 4;
#pragma unroll
  for (int r = 0; r < 4; ++r) {
    int m = m0 + r;
    float deg = acc1[(size_t)m * 24 + 20];
    float sdeg = acc2[(size_t)m * 24 + 20];
    float qv = acc[r] + sdeg * bsum + deg * bself;
    V[(size_t)m * 224 + col] = f2bf(qv * sc + deg * sh);
  }
}

// ---- h2pre prefill: sea1@We2 + deg*(bm2+be2) + x1[n] ---- block=208, grid=N
__global__ void h2pre_k(const float* __restrict__ acc1, const float* __restrict__ h1pre,
                        const float* __restrict__ x, const float* __restrict__ We2,
                        const float* __restrict__ bm2, const float* __restrict__ be2,
                        const float* __restrict__ st, float* __restrict__ h2pre) {
  int n = blockIdx.x, t = threadIdx.x;
  float deg = acc1[(size_t)n * 24 + 20];
  float e0 = acc1[(size_t)n * 24 + 16], e1 = acc1[(size_t)n * 24 + 17];
  float e2 = acc1[(size_t)n * 24 + 18], e3 = acc1[(size_t)n * 24 + 19];
  float x1n = (t < 192) ? (h1pre[(size_t)n * 192 + t] * st[t] + st[192 + t])
                        : x[(size_t)n * 16 + (t - 192)];
  h2pre[(size_t)n * 208 + t] = e0 * We2[t] + e1 * We2[208 + t] + e2 * We2[416 + t] +
                               e3 * We2[624 + t] + deg * (bm2[t] + be2[t]) + x1n;
}

// ---- BN column reduce ---- block=256, grid=ceil(N/128)
__global__ void bnred_k(const float* __restrict__ h, int N, int C, float* __restrict__ sums) {
  int t = threadIdx.x;
  if (t >= C) return;
  int r0 = blockIdx.x * 128;
  int r1 = min(r0 + 128, N);
  float s = 0.f, ss = 0.f;
  for (int n = r0; n < r1; ++n) {
    float v = h[(size_t)n * C + t];
    s += v;
    ss += v * v;
  }
  atomAddF(&sums[t], s);
  atomAddF(&sums[C + t], ss);
}

__global__ void bnfin_k(const float* __restrict__ sums, const float* __restrict__ g,
                        const float* __restrict__ be, int C, float Ninv, float* __restrict__ st) {
  int t = threadIdx.x;
  if (t >= C) return;
  float m = sums[t] * Ninv;
  float v = sums[C + t] * Ninv - m * m;
  float s = g[t] * rsqrtf(v + 1e-5f);
  st[t] = s;
  st[C + t] = be[t] - m * s;
}

// ---- pooling: x2 on the fly, sum + max per graph ---- grid=(64,8), block=256
__global__ void pool_k(const float* __restrict__ h2pre, const float* __restrict__ h1pre,
                       const float* __restrict__ x, const float* __restrict__ st,
                       const int* __restrict__ gstart, const int* __restrict__ gend,
                       float* __restrict__ psum, u32* __restrict__ pmaxu) {
  int b = blockIdx.x, sub = blockIdx.y;
  int s0 = gstart[b], e0 = gend[b];
  if (s0 > e0) return;
  int cnt = e0 - s0 + 1;
  int per = (cnt + 7) >> 3;
  int n0 = s0 + sub * per;
  int n1 = min(n0 + per, e0 + 1);
  if (n0 >= n1) return;
  const float* st1 = st;
  const float* st2 = st + 384;
  for (int f = threadIdx.x; f < 416; f += 256) {
    const float* src;
    int stride;
    float sc, sh;
    if (f < 208) { src = h2pre + f; stride = 208; sc = st2[f]; sh = st2[208 + f]; }
    else if (f < 400) { int j = f - 208; src = h1pre + j; stride = 192; sc = st1[j]; sh = st1[192 + j]; }
    else { src = x + (f - 400); stride = 16; sc = 1.f; sh = 0.f; }
    float s = 0.f, mx = -3.4e38f;
    for (int n = n0; n < n1; ++n) {
      float v = src[(size_t)n * stride] * sc + sh;
      s += v;
      mx = fmaxf(mx, v);
    }
    atomAddF(&psum[b * 416 + f], s);
    atomicMax(&pmaxu[b * 416 + f], fflip(mx));
  }
}

// ---- pooled -> bf16 A matrix [64 x 1248] ---- grid=64, block=256
__global__ void pooledprep_k(const float* __restrict__ psum, const u32* __restrict__ pmaxu,
                             const int* __restrict__ gstart, const int* __restrict__ gend,
                             u16* __restrict__ Apool) {
  int b = blockIdx.x, t = threadIdx.x;
  int cnt = gend[b] - gstart[b] + 1;
  float inv = 1.f / (float)max(cnt, 1);
  for (int f = t; f < 416; f += 256) {
    float s = psum[b * 416 + f];
    float m = funflip(pmaxu[b * 416 + f]);
    u16* row = Apool + (size_t)b * 1248;
    row[f] = f2bf(s);
    row[416 + f] = f2bf((cnt > 0) ? m : 0.f);
    row[832 + f] = f2bf(s * inv);
  }
}

// ---- MLP layer 1 via MFMA: hid = PReLU(Apool @ W1 + b1) ---- grid=(4,39), block=64
__global__ void mlpgemm_k(const u16* __restrict__ A, const u16* __restrict__ Bp,
                          const float* __restrict__ b1, const float* __restrict__ al,
                          float* __restrict__ hid) {
  int lane = threadIdx.x;
  int mt = blockIdx.x, nt = blockIdx.y;
  int rc = lane & 15, qd = lane >> 4;
  f32x4 acc = {0.f, 0.f, 0.f, 0.f};
  const u16* Ap = A + (size_t)(mt * 16 + rc) * 1248 + qd * 8;
  const u16* Bq = Bp + (size_t)(qd * 624 + nt * 16 + rc) * 8;
  for (int kb = 0; kb < 39; ++kb) {
    short8 av = *(const short8*)(Ap + kb * 32);
    short8 bv = *(const short8*)(Bq + (size_t)kb * 4 * 624 * 8);
    acc = __builtin_amdgcn_mfma_f32_16x16x32_bf16(av, bv, acc, 0, 0, 0);
  }
  int col = nt * 16 + rc;
  float bb = b1[col], alpha = al[0];
  int m0 = mt * 16 + qd * 4;
#pragma unroll
  for (int r = 0; r < 4; ++r) {
    float v = acc[r] + bb;
    hid[(size_t)(m0 + r) * 624 + col] = (v >= 0.f) ? v : alpha * v;
  }
}

// ---- logits + log_softmax ---- grid=64, block=64 (one wave)
__global__ void head_k(const float* __restrict__ hid, const float* __restrict__ W2,
                       const float* __restrict__ b2, float* __restrict__ out) {
  int b = blockIdx.x, t = threadIdx.x;
  float p0 = 0.f, p1 = 0.f;
  for (int k = t; k < 624; k += 64) {
    float h = hid[(size_t)b * 624 + k];
    p0 += h * W2[k * 2];
    p1 += h * W2[k * 2 + 1];
  }
#pragma unroll
  for (int off = 32; off > 0; off >>= 1) {
    p0 += __shfl_down(p0, off);
    p1 += __shfl_down(p1, off);
  }
  if (t == 0) {
    float l0 = p0 + b2[0], l1 = p1 + b2[1];
    float m = fmaxf(l0, l1);
    float lse = m + logf(expf(l0 - m) + expf(l1 - m));
    out[b * 2] = l0 - lse;
    out[b * 2 + 1] = l1 - lse;
  }
}

extern "C" void kernel_launch(void* const* d_in, const int* in_sizes, int n_in,
                              void* d_out, int out_size, void* d_ws, size_t ws_size,
                              hipStream_t stream) {
  const float* x = (const float*)d_in[0];
  const int* ei = (const int*)d_in[1];
  const float* ea = (const float*)d_in[2];
  const int* batch = (const int*)d_in[3];
  const float* Wm1 = (const float*)d_in[4];
  const float* bm1 = (const float*)d_in[5];
  const float* We1 = (const float*)d_in[6];
  const float* be1 = (const float*)d_in[7];
  const float* Ws1 = (const float*)d_in[8];
  const float* bs1 = (const float*)d_in[9];
  const float* g1 = (const float*)d_in[10];
  const float* bta1 = (const float*)d_in[11];
  const float* Wm2 = (const float*)d_in[12];
  const float* bm2 = (const float*)d_in[13];
  const float* We2 = (const float*)d_in[14];
  const float* be2 = (const float*)d_in[15];
  const float* g2 = (const float*)d_in[16];
  const float* bta2 = (const float*)d_in[17];
  const float* Wl1 = (const float*)d_in[18];
  const float* bl1 = (const float*)d_in[19];
  const float* alpha = (const float*)d_in[20];
  const float* Wl2 = (const float*)d_in[21];
  const float* bl2 = (const float*)d_in[22];
  float* out = (float*)d_out;

  const int N = in_sizes[3];      // 50000
  const int E = in_sizes[2] / 4;  // 800000
  const int MT = N / 16;          // 3125
  const int nb = (N + 255) / 256; // scan blocks (<=256 required)

  float* ws = (float*)d_ws;
  size_t o = 0;
  float* acc1 = ws + o;  o += (size_t)N * 24;
  float* acc2 = ws + o;  o += (size_t)N * 24;
  float* h1pre = ws + o; o += (size_t)N * 192;
  float* h2pre = ws + o; o += (size_t)N * 208;   // also aliased as CSR edge list (se)
  u16* U = (u16*)(ws + o);  o += (size_t)N * 32;   // N*64 u16
  u16* V = (u16*)(ws + o);  o += (size_t)N * 112;  // N*224 u16
  u16* Wp1 = (u16*)(ws + o); o += 6144;            // 64*192 u16
  u16* Wp2 = (u16*)(ws + o); o += 23296;           // 224*208 u16
  u16* Wp3 = (u16*)(ws + o); o += 389376;          // 1248*624 u16
  u16* Apool = (u16*)(ws + o); o += 39936;         // 64*1248 u16
  float* hid = ws + o;   o += 64 * 624;
  float* bns = ws + o;   o += 800;                 // bn1 sums(384) | bn2 sums(416)
  float* st = ws + o;    o += 800;                 // s1t1(384) | s2t2(416)
  float* psum = ws + o;  o += 64 * 416;
  u32* pmaxu = (u32*)(ws + o); o += 64 * 416;
  int* gstart = (int*)(ws + o); o += 64;
  int* gend = (int*)(ws + o);   o += 64;
  int* deg = (int*)(ws + o);    o += N;
  int* rowptr = (int*)(ws + o); o += N + 1;
  int* cur = (int*)(ws + o);    o += N + 1;
  int* bsum = (int*)(ws + o);   o += 256;
  int2* se = (int2*)h2pre;  // E int2 = 6.4 MB <= N*208*4B; h2pre written later

  hipMemsetAsync(deg, 0, (size_t)N * sizeof(int), stream);
  hipMemsetAsync(bns, 0, (size_t)(800 + 800 + 2 * 64 * 416) * sizeof(float), stream);

  int sb = (N + 255) / 256;  // 196 >= 224*208/256
  setup_k<<<sb, 256, 0, stream>>>(Wm1, We1, Ws1, Wm2, batch, Wp1, Wp2, gstart, gend, N);
  pack1_k<<<(1248 * 624 + 255) / 256, 256, 0, stream>>>(Wl1, Wp3);
  // CSR build
  count_k<<<(E + 255) / 256, 256, 0, stream>>>(ei, deg, E);
  scanA_k<<<nb, 256, 0, stream>>>(deg, bsum, N);
  scanB_k<<<1, 256, 0, stream>>>(bsum, nb);
  scanC_k<<<nb, 256, 0, stream>>>(deg, bsum, rowptr, cur, N);
  scatter_k<<<(E + 255) / 256, 256, 0, stream>>>(ei, cur, se, E);
  // layer 1
  gather1_k<<<(N + 63) / 64, 256, 0, stream>>>(se, rowptr, x, ea, acc1, N);
  u1h1_k<<<N, 192, 0, stream>>>(acc1, x, U, h1pre, bm1, be1, bs1);
  gemm_k<<<dim3(MT, 12), 64, 0, stream>>>(U, Wp1, h1pre, 64, 192);
  bnred_k<<<(N + 127) / 128, 256, 0, stream>>>(h1pre, N, 192, bns);
  bnfin_k<<<1, 256, 0, stream>>>(bns, g1, bta1, 192, 1.f / (float)N, st);
  // layer 2
  gather2_k<<<(N + 63) / 64, 256, 0, stream>>>(se, rowptr, acc1, acc2, N);
  u2v_k<<<N, 192, 0, stream>>>(acc1, acc2, U, V);
  gemmq_k<<<dim3(MT, 12), 64, 0, stream>>>(U, Wp1, acc1, acc2, bm1, be1, bs1, st, V);
  h2pre_k<<<N, 208, 0, stream>>>(acc1, h1pre, x, We2, bm2, be2, st, h2pre);
  gemm_k<<<dim3(MT, 13), 64, 0, stream>>>(V, Wp2, h2pre, 224, 208);
  bnred_k<<<(N + 127) / 128, 256, 0, stream>>>(h2pre, N, 208, bns + 384);
  bnfin_k<<<1, 256, 0, stream>>>(bns + 384, g2, bta2, 208, 1.f / (float)N, st + 384);
  // head
  pool_k<<<dim3(64, 8), 256, 0, stream>>>(h2pre, h1pre, x, st, gstart, gend, psum, pmaxu);
  pooledprep_k<<<64, 256, 0, stream>>>(psum, pmaxu, gstart, gend, Apool);
  mlpgemm_k<<<dim3(4, 39), 64, 0, stream>>>(Apool, Wp3, bl1, alpha, hid);
  head_k<<<64, 64, 0, stream>>>(hid, Wl2, bl2, out);
}

// Round 4
// 539.906 us; speedup vs baseline: 4.2395x; 1.1408x over previous
//
#include <hip/hip_runtime.h>

typedef __attribute__((ext_vector_type(8))) short short8;
typedef __attribute__((ext_vector_type(4))) float f32x4;
typedef unsigned short u16;
typedef unsigned int u32;

__device__ __forceinline__ u16 f2bf(float f) {
  u32 u = __float_as_uint(f);
  u = (u + 0x7fffu + ((u >> 16) & 1u)) >> 16;
  return (u16)u;
}
__device__ __forceinline__ void atomAddF(float* p, float v) { unsafeAtomicAdd(p, v); }
__device__ __forceinline__ u32 fflip(float f) {
  u32 u = __float_as_uint(f);
  return (u & 0x80000000u) ? ~u : (u | 0x80000000u);
}
__device__ __forceinline__ float funflip(u32 u) {
  return __uint_as_float((u & 0x80000000u) ? (u ^ 0x80000000u) : ~u);
}
__device__ __forceinline__ void add4(float4& a, const float4 b) {
  a.x += b.x; a.y += b.y; a.z += b.z; a.w += b.w;
}

// ---- setup: pack bf16 weights (MFMA B-frag layout) + find graph boundaries ----
__global__ void setup_k(const float* __restrict__ Wm1, const float* __restrict__ We1,
                        const float* __restrict__ Ws1, const float* __restrict__ Wm2,
                        const int* __restrict__ batch, u16* __restrict__ Wp1,
                        u16* __restrict__ Wp2, int* __restrict__ gstart,
                        int* __restrict__ gend, int N) {
  int tid = blockIdx.x * 256 + threadIdx.x;
  if (tid < 64 * 192) {  // Wcat1 = [Wm1(16); We1(4); Ws1(16)] rows, pad K to 64
    int k = tid / 192, n = tid % 192;
    float v = 0.f;
    if (k < 16) v = Wm1[k * 192 + n];
    else if (k < 20) v = We1[(k - 16) * 192 + n];
    else if (k < 36) v = Ws1[(k - 20) * 192 + n];
    Wp1[((k >> 3) * 192 + n) * 8 + (k & 7)] = f2bf(v);
  }
  if (tid < 224 * 208) {  // W_msg2, pad K 208->224
    int k = tid / 208, n = tid % 208;
    float v = (k < 208) ? Wm2[k * 208 + n] : 0.f;
    Wp2[((k >> 3) * 208 + n) * 8 + (k & 7)] = f2bf(v);
  }
  if (tid < N) {  // batch sorted -> unique writers
    int b = batch[tid];
    if (tid == 0 || batch[tid - 1] != b) gstart[b] = tid;
    if (tid == N - 1 || batch[tid + 1] != b) gend[b] = tid;
  }
}

// ---- pack W_l1 (1248x624) to bf16 B-frag layout ----
__global__ void pack1_k(const float* __restrict__ W1, u16* __restrict__ Wp3) {
  int tid = blockIdx.x * 256 + threadIdx.x;
  if (tid >= 1248 * 624) return;
  int k = tid / 624, n = tid % 624;
  Wp3[((size_t)(k >> 3) * 624 + n) * 8 + (k & 7)] = f2bf(W1[(size_t)k * 624 + n]);
}

// ---- CSR build: count -> scan -> scatter ----
__global__ void count_k(const int* __restrict__ ei, int* __restrict__ deg, int E) {
  int e = blockIdx.x * 256 + threadIdx.x;
  if (e >= E) return;
  atomicAdd(&deg[ei[E + e]], 1);
}

__global__ void scanA_k(const int* __restrict__ deg, int* __restrict__ bsum, int N) {
  __shared__ int sh[256];
  int t = threadIdx.x;
  int i = blockIdx.x * 256 + t;
  sh[t] = (i < N) ? deg[i] : 0;
  __syncthreads();
  for (int off = 128; off > 0; off >>= 1) {
    if (t < off) sh[t] += sh[t + off];
    __syncthreads();
  }
  if (t == 0) bsum[blockIdx.x] = sh[0];
}

__global__ void scanB_k(int* __restrict__ bsum, int nb) {  // nb <= 256, 1 block
  __shared__ int sh[256];
  int t = threadIdx.x;
  int v = (t < nb) ? bsum[t] : 0;
  sh[t] = v;
  __syncthreads();
  for (int off = 1; off < 256; off <<= 1) {
    int u = (t >= off) ? sh[t - off] : 0;
    __syncthreads();
    sh[t] += u;
    __syncthreads();
  }
  if (t < nb) bsum[t] = sh[t] - v;  // exclusive
}

__global__ void scanC_k(const int* __restrict__ deg, const int* __restrict__ bsum,
                        int* __restrict__ rowptr, int* __restrict__ cur, int N) {
  __shared__ int sh[256];
  int t = threadIdx.x;
  int i = blockIdx.x * 256 + t;
  int d = (i < N) ? deg[i] : 0;
  sh[t] = d;
  __syncthreads();
  for (int off = 1; off < 256; off <<= 1) {
    int u = (t >= off) ? sh[t - off] : 0;
    __syncthreads();
    sh[t] += u;
    __syncthreads();
  }
  int excl = sh[t] - d + bsum[blockIdx.x];
  if (i < N) {
    rowptr[i] = excl;
    cur[i] = excl;
    if (i == N - 1) rowptr[N] = excl + d;
  }
}

__global__ void scatter_k(const int* __restrict__ ei, int* __restrict__ cur,
                          int2* __restrict__ se, int E) {
  int e = blockIdx.x * 256 + threadIdx.x;
  if (e >= E) return;
  int s = ei[e], d = ei[E + e];
  int slot = atomicAdd(&cur[d], 1);
  se[slot] = make_int2(s, e);
}

// ---- gather pass 1: 4 lanes per node, quad shuffle-reduce ---- block=256
__global__ void gather1_k(const int2* __restrict__ se, const int* __restrict__ rowptr,
                          const float* __restrict__ x, const float* __restrict__ ea,
                          float* __restrict__ acc1, int N) {
  int tid = blockIdx.x * 256 + threadIdx.x;
  int n = tid >> 2, q = tid & 3;
  if (n >= N) return;
  int j0 = rowptr[n], j1 = rowptr[n + 1];
  float4 a0 = {0, 0, 0, 0}, a1 = a0, a2 = a0, a3 = a0, a4 = a0;
  for (int j = j0 + q; j < j1; j += 4) {
    int2 p = se[j];
    const float4* xs = (const float4*)(x + (size_t)p.x * 16);
    float4 w = *(const float4*)(ea + (size_t)p.y * 4);
    add4(a0, xs[0]); add4(a1, xs[1]); add4(a2, xs[2]); add4(a3, xs[3]); add4(a4, w);
  }
  float v[24] = {a0.x, a0.y, a0.z, a0.w, a1.x, a1.y, a1.z, a1.w,
                 a2.x, a2.y, a2.z, a2.w, a3.x, a3.y, a3.z, a3.w,
                 a4.x, a4.y, a4.z, a4.w, (float)(j1 - j0), 0.f, 0.f, 0.f};
#pragma unroll
  for (int i = 0; i < 20; ++i) {
    v[i] += __shfl_xor(v[i], 1);
    v[i] += __shfl_xor(v[i], 2);
  }
  float4* out = (float4*)(acc1 + (size_t)n * 24);
  out[q] = make_float4(v[q * 4], v[q * 4 + 1], v[q * 4 + 2], v[q * 4 + 3]);
  if (q < 2) out[4 + q] = make_float4(v[16 + q * 4], v[17 + q * 4], v[18 + q * 4], v[19 + q * 4]);
}

// ---- gather pass 2: acc2[n] = sum over in-edges of acc1[src][0..21) ---- block=256
__global__ void gather2_k(const int2* __restrict__ se, const int* __restrict__ rowptr,
                          const float* __restrict__ acc1, float* __restrict__ acc2, int N) {
  int tid = blockIdx.x * 256 + threadIdx.x;
  int n = tid >> 2, q = tid & 3;
  if (n >= N) return;
  int j0 = rowptr[n], j1 = rowptr[n + 1];
  float4 a0 = {0, 0, 0, 0}, a1 = a0, a2 = a0, a3 = a0, a4 = a0;
  float dg = 0.f;
  for (int j = j0 + q; j < j1; j += 4) {
    int s = se[j].x;
    const float4* ap = (const float4*)(acc1 + (size_t)s * 24);
    float4 t5 = ap[5];
    add4(a0, ap[0]); add4(a1, ap[1]); add4(a2, ap[2]); add4(a3, ap[3]); add4(a4, ap[4]);
    dg += t5.x;
  }
  float v[24] = {a0.x, a0.y, a0.z, a0.w, a1.x, a1.y, a1.z, a1.w,
                 a2.x, a2.y, a2.z, a2.w, a3.x, a3.y, a3.z, a3.w,
                 a4.x, a4.y, a4.z, a4.w, dg, 0.f, 0.f, 0.f};
#pragma unroll
  for (int i = 0; i < 21; ++i) {
    v[i] += __shfl_xor(v[i], 1);
    v[i] += __shfl_xor(v[i], 2);
  }
  float4* out = (float4*)(acc2 + (size_t)n * 24);
  out[q] = make_float4(v[q * 4], v[q * 4 + 1], v[q * 4 + 2], v[q * 4 + 3]);
  if (q < 2) out[4 + q] = make_float4(v[16 + q * 4], v[17 + q * 4], v[18 + q * 4], v[19 + q * 4]);
}

// ---- U1 build (bf16 [sx,sea,x] pad 64) ---- flat, block=256
__global__ void u1_k(const float* __restrict__ acc1, const float* __restrict__ x,
                     u16* __restrict__ U, int N) {
  int tid = blockIdx.x * 256 + threadIdx.x;
  if (tid >= N * 64) return;
  int n = tid >> 6, t = tid & 63;
  float v = 0.f;
  if (t < 20) v = acc1[(size_t)n * 24 + t];
  else if (t < 36) v = x[(size_t)n * 16 + (t - 20)];
  U[tid] = f2bf(v);
}

// ---- U2 build (bf16 [sx2,sea2,sx] pad 64) + V tail cols [192..224) ---- flat
__global__ void u2v_k(const float* __restrict__ acc1, const float* __restrict__ acc2,
                      u16* __restrict__ U, u16* __restrict__ V, int N) {
  int tid = blockIdx.x * 256 + threadIdx.x;
  if (tid >= N * 64) return;
  int n = tid >> 6, t = tid & 63;
  float v = 0.f;
  if (t < 20) v = acc2[(size_t)n * 24 + t];
  else if (t < 36) v = acc1[(size_t)n * 24 + (t - 20)];
  U[tid] = f2bf(v);
  if (t < 32) {
    float w = (t < 16) ? acc1[(size_t)n * 24 + t] : 0.f;
    V[(size_t)n * 224 + 192 + t] = f2bf(w);
  }
}

// ---- GEMM1: h1pre = U@Wp1 + deg*(bm1+be1) + bs1 ---- block=64(1 wave), grid=MT
__global__ void __launch_bounds__(64) gemm1_k(
    const u16* __restrict__ A, const u16* __restrict__ Bp, const float* __restrict__ acc1,
    const float* __restrict__ bm1, const float* __restrict__ be1,
    const float* __restrict__ bs1, float* __restrict__ h1pre) {
  int lane = threadIdx.x;
  int mt = blockIdx.x;
  int rc = lane & 15, qd = lane >> 4;
  f32x4 acc[12];
#pragma unroll
  for (int i = 0; i < 12; ++i) acc[i] = {0.f, 0.f, 0.f, 0.f};
  const u16* Ap = A + (size_t)(mt * 16 + rc) * 64 + qd * 8;
#pragma unroll
  for (int kb = 0; kb < 2; ++kb) {
    short8 av = *(const short8*)(Ap + kb * 32);
#pragma unroll
    for (int nt = 0; nt < 12; ++nt) {
      short8 bv = *(const short8*)(Bp + (size_t)((kb * 4 + qd) * 192 + nt * 16 + rc) * 8);
      acc[nt] = __builtin_amdgcn_mfma_f32_16x16x32_bf16(av, bv, acc[nt], 0, 0, 0);
    }
  }
  int m0 = mt * 16 + qd * 4;
  float deg[4];
#pragma unroll
  for (int r = 0; r < 4; ++r) deg[r] = acc1[(size_t)(m0 + r) * 24 + 20];
#pragma unroll
  for (int nt = 0; nt < 12; ++nt) {
    int col = nt * 16 + rc;
    float bb = bm1[col] + be1[col], bs = bs1[col];
#pragma unroll
    for (int r = 0; r < 4; ++r)
      h1pre[(size_t)(m0 + r) * 192 + col] = acc[nt][r] + deg[r] * bb + bs;
  }
}

// ---- GEMMQ2: V[.,0..192) = bf16((U2@Wp1 + sdeg*bsum + deg*bself)*s1 + deg*t1) ----
__global__ void __launch_bounds__(64) gemmq2_k(
    const u16* __restrict__ A, const u16* __restrict__ Bp, const float* __restrict__ acc1,
    const float* __restrict__ acc2, const float* __restrict__ bm1,
    const float* __restrict__ be1, const float* __restrict__ bs1,
    const float* __restrict__ st, u16* __restrict__ V) {
  int lane = threadIdx.x;
  int mt = blockIdx.x;
  int rc = lane & 15, qd = lane >> 4;
  f32x4 acc[12];
#pragma unroll
  for (int i = 0; i < 12; ++i) acc[i] = {0.f, 0.f, 0.f, 0.f};
  const u16* Ap = A + (size_t)(mt * 16 + rc) * 64 + qd * 8;
#pragma unroll
  for (int kb = 0; kb < 2; ++kb) {
    short8 av = *(const short8*)(Ap + kb * 32);
#pragma unroll
    for (int nt = 0; nt < 12; ++nt) {
      short8 bv = *(const short8*)(Bp + (size_t)((kb * 4 + qd) * 192 + nt * 16 + rc) * 8);
      acc[nt] = __builtin_amdgcn_mfma_f32_16x16x32_bf16(av, bv, acc[nt], 0, 0, 0);
    }
  }
  int m0 = mt * 16 + qd * 4;
  float deg[4], sdeg[4];
#pragma unroll
  for (int r = 0; r < 4; ++r) {
    deg[r] = acc1[(size_t)(m0 + r) * 24 + 20];
    sdeg[r] = acc2[(size_t)(m0 + r) * 24 + 20];
  }
#pragma unroll
  for (int nt = 0; nt < 12; ++nt) {
    int col = nt * 16 + rc;
    float sc = st[col], sh = st[192 + col];
    float bsum = bm1[col] + be1[col], bself = bs1[col];
#pragma unroll
    for (int r = 0; r < 4; ++r) {
      float qv = acc[nt][r] + sdeg[r] * bsum + deg[r] * bself;
      V[(size_t)(m0 + r) * 224 + col] = f2bf(qv * sc + deg[r] * sh);
    }
  }
}

// ---- GEMM2 fused: h2pre = V@Wp2 + e.We2 + deg*(bm2+be2) + x1 ---- block=64, grid=MT
__global__ void __launch_bounds__(64) gemm2_k(
    const u16* __restrict__ A, const u16* __restrict__ Bp, const float* __restrict__ acc1,
    const float* __restrict__ h1pre, const float* __restrict__ x,
    const float* __restrict__ We2, const float* __restrict__ bm2,
    const float* __restrict__ be2, const float* __restrict__ st,
    float* __restrict__ h2pre) {
  int lane = threadIdx.x;
  int mt = blockIdx.x;
  int rc = lane & 15, qd = lane >> 4;
  f32x4 acc[13];
#pragma unroll
  for (int i = 0; i < 13; ++i) acc[i] = {0.f, 0.f, 0.f, 0.f};
  const u16* Ap = A + (size_t)(mt * 16 + rc) * 224 + qd * 8;
#pragma unroll
  for (int kb = 0; kb < 7; ++kb) {
    short8 av = *(const short8*)(Ap + kb * 32);
#pragma unroll
    for (int nt = 0; nt < 13; ++nt) {
      short8 bv = *(const short8*)(Bp + (size_t)((kb * 4 + qd) * 208 + nt * 16 + rc) * 8);
      acc[nt] = __builtin_amdgcn_mfma_f32_16x16x32_bf16(av, bv, acc[nt], 0, 0, 0);
    }
  }
  int m0 = mt * 16 + qd * 4;
  float e0[4], e1[4], e2[4], e3[4], deg[4];
#pragma unroll
  for (int r = 0; r < 4; ++r) {
    const float* a = acc1 + (size_t)(m0 + r) * 24;
    e0[r] = a[16]; e1[r] = a[17]; e2[r] = a[18]; e3[r] = a[19]; deg[r] = a[20];
  }
#pragma unroll
  for (int nt = 0; nt < 13; ++nt) {
    int col = nt * 16 + rc;
    float w0 = We2[col], w1 = We2[208 + col], w2 = We2[416 + col], w3 = We2[624 + col];
    float bb = bm2[col] + be2[col];
    bool c192 = col < 192;
    float sc = c192 ? st[col] : 0.f;
    float sh = c192 ? st[192 + col] : 0.f;
#pragma unroll
    for (int r = 0; r < 4; ++r) {
      int m = m0 + r;
      float x1 = c192 ? (h1pre[(size_t)m * 192 + col] * sc + sh)
                      : x[(size_t)m * 16 + (col - 192)];
      h2pre[(size_t)m * 208 + col] =
          acc[nt][r] + e0[r] * w0 + e1[r] * w1 + e2[r] * w2 + e3[r] * w3 + deg[r] * bb + x1;
    }
  }
}

// ---- BN column reduce ---- block=256, grid=ceil(N/128)
__global__ void bnred_k(const float* __restrict__ h, int N, int C, float* __restrict__ sums) {
  int t = threadIdx.x;
  if (t >= C) return;
  int r0 = blockIdx.x * 128;
  int r1 = min(r0 + 128, N);
  float s = 0.f, ss = 0.f;
  for (int n = r0; n < r1; ++n) {
    float v = h[(size_t)n * C + t];
    s += v;
    ss += v * v;
  }
  atomAddF(&sums[t], s);
  atomAddF(&sums[C + t], ss);
}

__global__ void bnfin_k(const float* __restrict__ sums, const float* __restrict__ g,
                        const float* __restrict__ be, int C, float Ninv, float* __restrict__ st) {
  int t = threadIdx.x;
  if (t >= C) return;
  float m = sums[t] * Ninv;
  float v = sums[C + t] * Ninv - m * m;
  float s = g[t] * rsqrtf(v + 1e-5f);
  st[t] = s;
  st[C + t] = be[t] - m * s;
}

// ---- pooling: x2 on the fly, sum + max per graph ---- grid=(64,8), block=256
__global__ void pool_k(const float* __restrict__ h2pre, const float* __restrict__ h1pre,
                       const float* __restrict__ x, const float* __restrict__ st,
                       const int* __restrict__ gstart, const int* __restrict__ gend,
                       float* __restrict__ psum, u32* __restrict__ pmaxu) {
  int b = blockIdx.x, sub = blockIdx.y;
  int s0 = gstart[b], e0 = gend[b];
  if (s0 > e0) return;
  int cnt = e0 - s0 + 1;
  int per = (cnt + 7) >> 3;
  int n0 = s0 + sub * per;
  int n1 = min(n0 + per, e0 + 1);
  if (n0 >= n1) return;
  const float* st1 = st;
  const float* st2 = st + 384;
  for (int f = threadIdx.x; f < 416; f += 256) {
    const float* src;
    int stride;
    float sc, sh;
    if (f < 208) { src = h2pre + f; stride = 208; sc = st2[f]; sh = st2[208 + f]; }
    else if (f < 400) { int j = f - 208; src = h1pre + j; stride = 192; sc = st1[j]; sh = st1[192 + j]; }
    else { src = x + (f - 400); stride = 16; sc = 1.f; sh = 0.f; }
    float s = 0.f, mx = -3.4e38f;
    for (int n = n0; n < n1; ++n) {
      float v = src[(size_t)n * stride] * sc + sh;
      s += v;
      mx = fmaxf(mx, v);
    }
    atomAddF(&psum[b * 416 + f], s);
    atomicMax(&pmaxu[b * 416 + f], fflip(mx));
  }
}

// ---- pooled -> bf16 A matrix [64 x 1248] ---- grid=64, block=256
__global__ void pooledprep_k(const float* __restrict__ psum, const u32* __restrict__ pmaxu,
                             const int* __restrict__ gstart, const int* __restrict__ gend,
                             u16* __restrict__ Apool) {
  int b = blockIdx.x, t = threadIdx.x;
  int cnt = gend[b] - gstart[b] + 1;
  float inv = 1.f / (float)max(cnt, 1);
  for (int f = t; f < 416; f += 256) {
    float s = psum[b * 416 + f];
    float m = funflip(pmaxu[b * 416 + f]);
    u16* row = Apool + (size_t)b * 1248;
    row[f] = f2bf(s);
    row[416 + f] = f2bf((cnt > 0) ? m : 0.f);
    row[832 + f] = f2bf(s * inv);
  }
}

// ---- MLP layer 1 via MFMA: hid = PReLU(Apool @ W1 + b1) ---- grid=(4,39), block=64
__global__ void mlpgemm_k(const u16* __restrict__ A, const u16* __restrict__ Bp,
                          const float* __restrict__ b1, const float* __restrict__ al,
                          float* __restrict__ hid) {
  int lane = threadIdx.x;
  int mt = blockIdx.x, nt = blockIdx.y;
  int rc = lane & 15, qd = lane >> 4;
  f32x4 acc = {0.f, 0.f, 0.f, 0.f};
  const u16* Ap = A + (size_t)(mt * 16 + rc) * 1248 + qd * 8;
  const u16* Bq = Bp + (size_t)(qd * 624 + nt * 16 + rc) * 8;
  for (int kb = 0; kb < 39; ++kb) {
    short8 av = *(const short8*)(Ap + kb * 32);
    short8 bv = *(const short8*)(Bq + (size_t)kb * 4 * 624 * 8);
    acc = __builtin_amdgcn_mfma_f32_16x16x32_bf16(av, bv, acc, 0, 0, 0);
  }
  int col = nt * 16 + rc;
  float bb = b1[col], alpha = al[0];
  int m0 = mt * 16 + qd * 4;
#pragma unroll
  for (int r = 0; r < 4; ++r) {
    float v = acc[r] + bb;
    hid[(size_t)(m0 + r) * 624 + col] = (v >= 0.f) ? v : alpha * v;
  }
}

// ---- logits + log_softmax ---- grid=64, block=64 (one wave)
__global__ void head_k(const float* __restrict__ hid, const float* __restrict__ W2,
                       const float* __restrict__ b2, float* __restrict__ out) {
  int b = blockIdx.x, t = threadIdx.x;
  float p0 = 0.f, p1 = 0.f;
  for (int k = t; k < 624; k += 64) {
    float h = hid[(size_t)b * 624 + k];
    p0 += h * W2[k * 2];
    p1 += h * W2[k * 2 + 1];
  }
#pragma unroll
  for (int off = 32; off > 0; off >>= 1) {
    p0 += __shfl_down(p0, off);
    p1 += __shfl_down(p1, off);
  }
  if (t == 0) {
    float l0 = p0 + b2[0], l1 = p1 + b2[1];
    float m = fmaxf(l0, l1);
    float lse = m + logf(expf(l0 - m) + expf(l1 - m));
    out[b * 2] = l0 - lse;
    out[b * 2 + 1] = l1 - lse;
  }
}

extern "C" void kernel_launch(void* const* d_in, const int* in_sizes, int n_in,
                              void* d_out, int out_size, void* d_ws, size_t ws_size,
                              hipStream_t stream) {
  const float* x = (const float*)d_in[0];
  const int* ei = (const int*)d_in[1];
  const float* ea = (const float*)d_in[2];
  const int* batch = (const int*)d_in[3];
  const float* Wm1 = (const float*)d_in[4];
  const float* bm1 = (const float*)d_in[5];
  const float* We1 = (const float*)d_in[6];
  const float* be1 = (const float*)d_in[7];
  const float* Ws1 = (const float*)d_in[8];
  const float* bs1 = (const float*)d_in[9];
  const float* g1 = (const float*)d_in[10];
  const float* bta1 = (const float*)d_in[11];
  const float* Wm2 = (const float*)d_in[12];
  const float* bm2 = (const float*)d_in[13];
  const float* We2 = (const float*)d_in[14];
  const float* be2 = (const float*)d_in[15];
  const float* g2 = (const float*)d_in[16];
  const float* bta2 = (const float*)d_in[17];
  const float* Wl1 = (const float*)d_in[18];
  const float* bl1 = (const float*)d_in[19];
  const float* alpha = (const float*)d_in[20];
  const float* Wl2 = (const float*)d_in[21];
  const float* bl2 = (const float*)d_in[22];
  float* out = (float*)d_out;

  const int N = in_sizes[3];      // 50000
  const int E = in_sizes[2] / 4;  // 800000
  const int MT = N / 16;          // 3125
  const int nb = (N + 255) / 256; // scan blocks (<=256 required)

  float* ws = (float*)d_ws;
  size_t o = 0;
  float* acc1 = ws + o;  o += (size_t)N * 24;
  float* acc2 = ws + o;  o += (size_t)N * 24;
  float* h1pre = ws + o; o += (size_t)N * 192;
  float* h2pre = ws + o; o += (size_t)N * 208;   // also aliased as CSR edge list (se)
  u16* U = (u16*)(ws + o);  o += (size_t)N * 32;   // N*64 u16
  u16* V = (u16*)(ws + o);  o += (size_t)N * 112;  // N*224 u16
  u16* Wp1 = (u16*)(ws + o); o += 6144;            // 64*192 u16
  u16* Wp2 = (u16*)(ws + o); o += 23296;           // 224*208 u16
  u16* Wp3 = (u16*)(ws + o); o += 389376;          // 1248*624 u16
  u16* Apool = (u16*)(ws + o); o += 39936;         // 64*1248 u16
  float* hid = ws + o;   o += 64 * 624;
  float* bns = ws + o;   o += 800;                 // bn1 sums(384) | bn2 sums(416)
  float* st = ws + o;    o += 800;                 // s1t1(384) | s2t2(416)
  float* psum = ws + o;  o += 64 * 416;
  u32* pmaxu = (u32*)(ws + o); o += 64 * 416;
  int* gstart = (int*)(ws + o); o += 64;
  int* gend = (int*)(ws + o);   o += 64;
  int* deg = (int*)(ws + o);    o += N;
  int* rowptr = (int*)(ws + o); o += N + 1;
  int* cur = (int*)(ws + o);    o += N + 1;
  int* bsum = (int*)(ws + o);   o += 256;
  int2* se = (int2*)h2pre;  // E int2 = 6.4 MB <= N*208*4B; h2pre written later

  hipMemsetAsync(deg, 0, (size_t)N * sizeof(int), stream);
  hipMemsetAsync(bns, 0, (size_t)(800 + 800 + 2 * 64 * 416) * sizeof(float), stream);

  int sb = (N + 255) / 256;  // 196 >= 224*208/256
  setup_k<<<sb, 256, 0, stream>>>(Wm1, We1, Ws1, Wm2, batch, Wp1, Wp2, gstart, gend, N);
  pack1_k<<<(1248 * 624 + 255) / 256, 256, 0, stream>>>(Wl1, Wp3);
  // CSR build
  count_k<<<(E + 255) / 256, 256, 0, stream>>>(ei, deg, E);
  scanA_k<<<nb, 256, 0, stream>>>(deg, bsum, N);
  scanB_k<<<1, 256, 0, stream>>>(bsum, nb);
  scanC_k<<<nb, 256, 0, stream>>>(deg, bsum, rowptr, cur, N);
  scatter_k<<<(E + 255) / 256, 256, 0, stream>>>(ei, cur, se, E);
  // layer 1
  gather1_k<<<(N + 63) / 64, 256, 0, stream>>>(se, rowptr, x, ea, acc1, N);
  u1_k<<<(N * 64 + 255) / 256, 256, 0, stream>>>(acc1, x, U, N);
  gemm1_k<<<MT, 64, 0, stream>>>(U, Wp1, acc1, bm1, be1, bs1, h1pre);
  bnred_k<<<(N + 127) / 128, 256, 0, stream>>>(h1pre, N, 192, bns);
  bnfin_k<<<1, 256, 0, stream>>>(bns, g1, bta1, 192, 1.f / (float)N, st);
  // layer 2
  gather2_k<<<(N + 63) / 64, 256, 0, stream>>>(se, rowptr, acc1, acc2, N);
  u2v_k<<<(N * 64 + 255) / 256, 256, 0, stream>>>(acc1, acc2, U, V, N);
  gemmq2_k<<<MT, 64, 0, stream>>>(U, Wp1, acc1, acc2, bm1, be1, bs1, st, V);
  gemm2_k<<<MT, 64, 0, stream>>>(V, Wp2, acc1, h1pre, x, We2, bm2, be2, st, h2pre);
  bnred_k<<<(N + 127) / 128, 256, 0, stream>>>(h2pre, N, 208, bns + 384);
  bnfin_k<<<1, 256, 0, stream>>>(bns + 384, g2, bta2, 208, 1.f / (float)N, st + 384);
  // head
  pool_k<<<dim3(64, 8), 256, 0, stream>>>(h2pre, h1pre, x, st, gstart, gend, psum, pmaxu);
  pooledprep_k<<<64, 256, 0, stream>>>(psum, pmaxu, gstart, gend, Apool);
  mlpgemm_k<<<dim3(4, 39), 64, 0, stream>>>(Apool, Wp3, bl1, alpha, hid);
  head_k<<<64, 64, 0, stream>>>(hid, Wl2, bl2, out);
}